// Round 1
// baseline (1018.374 us; speedup 1.0000x reference)
//
#include <hip/hip_runtime.h>
#include <hip/hip_bf16.h>

// Problem constants (fixed by the reference)
#define E    256
#define NH   8
#define NL   3
#define NP   4
#define HD   32
#define LQ   13125   // = Lv = 10000 + 2500 + 625

// ---------------------------------------------------------------------------
// GEMM: C[M,256] = A[M,256] @ W[256,256] + bias.  16 rows per block staged in
// LDS, one output column per thread, broadcast LDS reads (no bank conflicts).
// Safe to run in-place (A == C): each block only reads its own 16 rows, and
// reads them entirely into LDS before any global write.
// ---------------------------------------------------------------------------
__global__ __launch_bounds__(256) void gemm256(
    const float* __restrict__ A, const float* __restrict__ W,
    const float* __restrict__ bias, float* __restrict__ C, int M) {
  __shared__ float As[16][E];
  const int tid = threadIdx.x;
  const int row0 = blockIdx.x * 16;

  for (int i = tid; i < 16 * E; i += 256) {
    int r = i >> 8, c = i & (E - 1);
    int gr = row0 + r;
    As[r][c] = (gr < M) ? A[(size_t)gr * E + c] : 0.f;
  }
  __syncthreads();

  const int col = tid;
  float acc[16];
#pragma unroll
  for (int r = 0; r < 16; ++r) acc[r] = 0.f;

  const float* Wp = W + col;
  for (int k = 0; k < E; k += 4) {
    float w0 = Wp[(size_t)(k + 0) * E];
    float w1 = Wp[(size_t)(k + 1) * E];
    float w2 = Wp[(size_t)(k + 2) * E];
    float w3 = Wp[(size_t)(k + 3) * E];
#pragma unroll
    for (int r = 0; r < 16; ++r) {
      const float4 a = *(const float4*)&As[r][k];
      acc[r] += a.x * w0 + a.y * w1 + a.z * w2 + a.w * w3;
    }
  }

  const float b = bias[col];
#pragma unroll
  for (int r = 0; r < 16; ++r) {
    int gr = row0 + r;
    if (gr < M) C[(size_t)gr * E + col] = acc[r] + b;
  }
}

// ---------------------------------------------------------------------------
// Offsets + attention weights + softmax.  16 query rows per block.
// Combined 288 output columns: [0,192) -> Woff, [192,288) -> Watt.
// Writes pixel-space sampling coords directly:
//   x_pix = ref_x * W_l + off_x - 0.5 ;  y_pix = ref_y * H_l + off_y - 0.5
// sampXY layout: (g, h, l, p, xy) flat = g*192 + col   (same order as Woff cols)
// sampW  layout: (g, h, l, p)     flat = g*96  + h*12 + l*4 + p
// ---------------------------------------------------------------------------
__global__ __launch_bounds__(256) void offatt(
    const float* __restrict__ Q, const float* __restrict__ ref,
    const float* __restrict__ Woff, const float* __restrict__ boff,
    const float* __restrict__ Watt, const float* __restrict__ batt,
    float* __restrict__ sampXY, float* __restrict__ sampW, int M) {
  __shared__ float Qs[16][E];
  __shared__ float atts[16][96];
  const int tid = threadIdx.x;
  const int row0 = blockIdx.x * 16;

  for (int i = tid; i < 16 * E; i += 256) {
    int r = i >> 8, c = i & (E - 1);
    int gr = row0 + r;
    Qs[r][c] = (gr < M) ? Q[(size_t)gr * E + c] : 0.f;
  }
  __syncthreads();

  for (int cc = tid; cc < 288; cc += 256) {
    const bool isOff = cc < 192;
    const int col = isOff ? cc : cc - 192;
    const int ldw = isOff ? 192 : 96;
    const float* Wp = (isOff ? Woff : Watt) + col;

    float acc[16];
#pragma unroll
    for (int r = 0; r < 16; ++r) acc[r] = 0.f;
    for (int k = 0; k < E; k += 4) {
      float w0 = Wp[(size_t)(k + 0) * ldw];
      float w1 = Wp[(size_t)(k + 1) * ldw];
      float w2 = Wp[(size_t)(k + 2) * ldw];
      float w3 = Wp[(size_t)(k + 3) * ldw];
#pragma unroll
      for (int r = 0; r < 16; ++r) {
        const float4 a = *(const float4*)&Qs[r][k];
        acc[r] += a.x * w0 + a.y * w1 + a.z * w2 + a.w * w3;
      }
    }

    if (isOff) {
      const float bo_ = boff[col];
      const int rem = col % 24;          // col = h*24 + l*8 + p*2 + xy
      const int l = rem >> 3;
      const int xy = col & 1;
      // levels are square (100,50,25) so W_l == H_l, but keep it explicit:
      const float S = (l == 0) ? 100.f : (l == 1 ? 50.f : 25.f);
      for (int r = 0; r < 16; ++r) {
        int g = row0 + r;
        if (g >= M) break;
        float rp = ref[(size_t)g * (NL * 2) + l * 2 + xy];
        sampXY[(size_t)g * 192 + col] = rp * S + acc[r] + bo_ - 0.5f;
      }
    } else {
      const float ba = batt[col];
#pragma unroll
      for (int r = 0; r < 16; ++r) atts[r][col] = acc[r] + ba;
    }
  }
  __syncthreads();

  // softmax over the 12 (l,p) values per (row, head): 128 pairs
  if (tid < 128) {
    const int r = tid >> 3, h = tid & 7;
    const int g = row0 + r;
    if (g < M) {
      const float* a = &atts[r][h * 12];
      float m = a[0];
#pragma unroll
      for (int j = 1; j < 12; ++j) m = fmaxf(m, a[j]);
      float e[12], s = 0.f;
#pragma unroll
      for (int j = 0; j < 12; ++j) { e[j] = expf(a[j] - m); s += e[j]; }
      const float inv = 1.f / s;
#pragma unroll
      for (int j = 0; j < 12; ++j)
        sampW[(size_t)g * 96 + h * 12 + j] = e[j] * inv;
    }
  }
}

// ---------------------------------------------------------------------------
// Bilinear sampling + attention-weighted accumulation.
// 8 groups of 32 lanes per block; each group = one (g, h); lane = channel d.
// v layout: (b, pos, h, d) flat = (b*LQ + pos)*E + h*HD + d  (GEMM output).
// Writes mid (== d_out) at (g, h, d).
// ---------------------------------------------------------------------------
__global__ __launch_bounds__(256) void deform_sample(
    const float* __restrict__ v, const float* __restrict__ sampXY,
    const float* __restrict__ sampW, float* __restrict__ mid, int M) {
  const int tid = threadIdx.x;
  const int gh = blockIdx.x * 8 + (tid >> 5);
  if (gh >= M * NH) return;
  const int d = tid & 31;
  const int g = gh >> 3;
  const int h = gh & 7;
  const int b = g / LQ;

  const float* xy = sampXY + (size_t)g * 192 + h * 24;
  const float* aw = sampW + (size_t)g * 96 + h * 12;
  const float* vb = v + ((size_t)b * LQ) * E + h * HD + d;

  const int Wl_[3] = {100, 50, 25};
  const int loff_[3] = {0, 10000, 12500};

  float acc = 0.f;
#pragma unroll
  for (int l = 0; l < NL; ++l) {
    const int Wl = Wl_[l], Hl = Wl_[l];
    const float* vl = vb + (size_t)loff_[l] * E;
#pragma unroll
    for (int p = 0; p < NP; ++p) {
      const float x = xy[l * 8 + p * 2 + 0];
      const float y = xy[l * 8 + p * 2 + 1];
      const float w = aw[l * 4 + p];
      const float fx = floorf(x), fy = floorf(y);
      const int x0 = (int)fx, y0 = (int)fy;
      const float wx1 = x - fx, wy1 = y - fy;
      const float wx0 = 1.f - wx1, wy0 = 1.f - wy1;
#pragma unroll
      for (int cy = 0; cy < 2; ++cy) {
        const int yi = y0 + cy;
        const float wy = cy ? wy1 : wy0;
        if (yi < 0 || yi >= Hl) continue;
#pragma unroll
        for (int cx = 0; cx < 2; ++cx) {
          const int xi = x0 + cx;
          const float wx = cx ? wx1 : wx0;
          if (xi < 0 || xi >= Wl) continue;
          acc += (w * wx * wy) * vl[(size_t)(yi * Wl + xi) * E];
        }
      }
    }
  }
  mid[(size_t)g * E + h * HD + d] = acc;
}

// ---------------------------------------------------------------------------
extern "C" void kernel_launch(void* const* d_in, const int* in_sizes, int n_in,
                              void* d_out, int out_size, void* d_ws, size_t ws_size,
                              hipStream_t stream) {
  const float* query = (const float*)d_in[0];
  const float* refpt = (const float*)d_in[1];
  const float* value = (const float*)d_in[2];
  // d_in[3] = value_spatial_shapes (static, hardcoded)
  const float* Wv   = (const float*)d_in[4];
  const float* bv   = (const float*)d_in[5];
  const float* Woff = (const float*)d_in[6];
  const float* boff = (const float*)d_in[7];
  const float* Watt = (const float*)d_in[8];
  const float* batt = (const float*)d_in[9];
  const float* Wo   = (const float*)d_in[10];
  const float* bo   = (const float*)d_in[11];

  const int M = in_sizes[0] / E;  // B * Lq = 52500

  float* ws = (float*)d_ws;
  float* v      = ws;                       // M*256 = 13,440,000 floats
  float* sampXY = v + (size_t)M * E;        // M*192 = 10,080,000
  float* sampW  = sampXY + (size_t)M * 192; // M*96  =  5,040,000
  float* mid    = (float*)d_out;            // in-place with output

  const int rowBlocks = (M + 15) / 16;

  // 1. value projection -> v
  gemm256<<<rowBlocks, 256, 0, stream>>>(value, Wv, bv, v, M);
  // 2. sampling locations + softmax weights
  offatt<<<rowBlocks, 256, 0, stream>>>(query, refpt, Woff, boff, Watt, batt,
                                        sampXY, sampW, M);
  // 3. deformable bilinear sampling -> mid (= d_out)
  deform_sample<<<(M * NH + 7) / 8, 256, 0, stream>>>(v, sampXY, sampW, mid, M);
  // 4. output projection, in-place on d_out
  gemm256<<<rowBlocks, 256, 0, stream>>>(mid, Wo, bo, (float*)d_out, M);
}

// Round 2
// 700.845 us; speedup vs baseline: 1.4531x; 1.4531x over previous
//
#include <hip/hip_runtime.h>
#include <hip/hip_bf16.h>

// Problem constants (fixed by the reference)
#define E    256
#define NH   8
#define NL   3
#define NP   4
#define HD   32
#define LQ   13125   // = Lv = 10000 + 2500 + 625

// ---------------------------------------------------------------------------
// GEMM: C[M,256] = A[M,256] @ W[256,256] + bias.  16 rows per block staged in
// LDS, one output column per thread, broadcast LDS reads (no bank conflicts).
// Safe to run in-place (A == C): each block only reads its own 16 rows, and
// reads them entirely into LDS before any global write.
// ---------------------------------------------------------------------------
__global__ __launch_bounds__(256) void gemm256(
    const float* __restrict__ A, const float* __restrict__ W,
    const float* __restrict__ bias, float* __restrict__ C, int M) {
  __shared__ float As[16][E];
  const int tid = threadIdx.x;
  const int row0 = blockIdx.x * 16;

  for (int i = tid; i < 16 * E; i += 256) {
    int r = i >> 8, c = i & (E - 1);
    int gr = row0 + r;
    As[r][c] = (gr < M) ? A[(size_t)gr * E + c] : 0.f;
  }
  __syncthreads();

  const int col = tid;
  float acc[16];
#pragma unroll
  for (int r = 0; r < 16; ++r) acc[r] = 0.f;

  const float* Wp = W + col;
  for (int k = 0; k < E; k += 4) {
    float w0 = Wp[(size_t)(k + 0) * E];
    float w1 = Wp[(size_t)(k + 1) * E];
    float w2 = Wp[(size_t)(k + 2) * E];
    float w3 = Wp[(size_t)(k + 3) * E];
#pragma unroll
    for (int r = 0; r < 16; ++r) {
      const float4 a = *(const float4*)&As[r][k];
      acc[r] += a.x * w0 + a.y * w1 + a.z * w2 + a.w * w3;
    }
  }

  const float b = bias[col];
#pragma unroll
  for (int r = 0; r < 16; ++r) {
    int gr = row0 + r;
    if (gr < M) C[(size_t)gr * E + col] = acc[r] + b;
  }
}

// ---------------------------------------------------------------------------
// Offsets + attention weights + softmax.  16 query rows per block.
// Combined 288 output columns: [0,192) -> Woff, [192,288) -> Watt.
// Writes pixel-space sampling coords directly:
//   x_pix = ref_x * W_l + off_x - 0.5 ;  y_pix = ref_y * H_l + off_y - 0.5
// sampXY layout: (g, h, l, p, xy) flat = g*192 + col   (same order as Woff cols)
// sampW  layout: (g, h, l, p)     flat = g*96  + h*12 + l*4 + p
// ---------------------------------------------------------------------------
__global__ __launch_bounds__(256) void offatt(
    const float* __restrict__ Q, const float* __restrict__ ref,
    const float* __restrict__ Woff, const float* __restrict__ boff,
    const float* __restrict__ Watt, const float* __restrict__ batt,
    float* __restrict__ sampXY, float* __restrict__ sampW, int M) {
  __shared__ float Qs[16][E];
  __shared__ float atts[16][96];
  const int tid = threadIdx.x;
  const int row0 = blockIdx.x * 16;

  for (int i = tid; i < 16 * E; i += 256) {
    int r = i >> 8, c = i & (E - 1);
    int gr = row0 + r;
    Qs[r][c] = (gr < M) ? Q[(size_t)gr * E + c] : 0.f;
  }
  __syncthreads();

  for (int cc = tid; cc < 288; cc += 256) {
    const bool isOff = cc < 192;
    const int col = isOff ? cc : cc - 192;
    const int ldw = isOff ? 192 : 96;
    const float* Wp = (isOff ? Woff : Watt) + col;

    float acc[16];
#pragma unroll
    for (int r = 0; r < 16; ++r) acc[r] = 0.f;
    for (int k = 0; k < E; k += 4) {
      float w0 = Wp[(size_t)(k + 0) * ldw];
      float w1 = Wp[(size_t)(k + 1) * ldw];
      float w2 = Wp[(size_t)(k + 2) * ldw];
      float w3 = Wp[(size_t)(k + 3) * ldw];
#pragma unroll
      for (int r = 0; r < 16; ++r) {
        const float4 a = *(const float4*)&Qs[r][k];
        acc[r] += a.x * w0 + a.y * w1 + a.z * w2 + a.w * w3;
      }
    }

    if (isOff) {
      const float bo_ = boff[col];
      const int rem = col % 24;          // col = h*24 + l*8 + p*2 + xy
      const int l = rem >> 3;
      const int xy = col & 1;
      // levels are square (100,50,25) so W_l == H_l, but keep it explicit:
      const float S = (l == 0) ? 100.f : (l == 1 ? 50.f : 25.f);
      for (int r = 0; r < 16; ++r) {
        int g = row0 + r;
        if (g >= M) break;
        float rp = ref[(size_t)g * (NL * 2) + l * 2 + xy];
        sampXY[(size_t)g * 192 + col] = rp * S + acc[r] + bo_ - 0.5f;
      }
    } else {
      const float ba = batt[col];
#pragma unroll
      for (int r = 0; r < 16; ++r) atts[r][col] = acc[r] + ba;
    }
  }
  __syncthreads();

  // softmax over the 12 (l,p) values per (row, head): 128 pairs
  if (tid < 128) {
    const int r = tid >> 3, h = tid & 7;
    const int g = row0 + r;
    if (g < M) {
      const float* a = &atts[r][h * 12];
      float m = a[0];
#pragma unroll
      for (int j = 1; j < 12; ++j) m = fmaxf(m, a[j]);
      float e[12], s = 0.f;
#pragma unroll
      for (int j = 0; j < 12; ++j) { e[j] = expf(a[j] - m); s += e[j]; }
      const float inv = 1.f / s;
#pragma unroll
      for (int j = 0; j < 12; ++j)
        sampW[(size_t)g * 96 + h * 12 + j] = e[j] * inv;
    }
  }
}

// ---------------------------------------------------------------------------
// Bilinear sampling + attention-weighted accumulation, float4 version.
// 8 lanes per (g, h) group; lane owns 4 channels.  256-thread block = 32
// groups; one wave64 covers 8 groups, so one global_load_dwordx4 fetches a
// full 128B corner slice per group (4x fewer VMEM instructions than scalar).
// Branchless corner handling: clamped indices + zeroed weights.
// ---------------------------------------------------------------------------
__global__ __launch_bounds__(256) void deform_sample4(
    const float* __restrict__ v, const float* __restrict__ sampXY,
    const float* __restrict__ sampW, float* __restrict__ mid, int M) {
  const int tid = threadIdx.x;
  const int gidx = blockIdx.x * 32 + (tid >> 3);
  if (gidx >= M * NH) return;
  const int d4 = (tid & 7) << 2;   // channel offset (4 floats per lane)
  const int g = gidx >> 3;
  const int h = gidx & 7;
  const int b = g / LQ;

  // hoist coords + weights into registers (16B-aligned: h*24*4=96B, h*12*4=48B)
  const float4* xy4 = (const float4*)(sampXY + (size_t)g * 192 + h * 24);
  const float4* aw4 = (const float4*)(sampW + (size_t)g * 96 + h * 12);
  float xy[24], aw[12];
#pragma unroll
  for (int i = 0; i < 6; ++i) {
    float4 t = xy4[i];
    xy[4 * i + 0] = t.x; xy[4 * i + 1] = t.y;
    xy[4 * i + 2] = t.z; xy[4 * i + 3] = t.w;
  }
#pragma unroll
  for (int i = 0; i < 3; ++i) {
    float4 t = aw4[i];
    aw[4 * i + 0] = t.x; aw[4 * i + 1] = t.y;
    aw[4 * i + 2] = t.z; aw[4 * i + 3] = t.w;
  }

  const float* vb = v + ((size_t)b * LQ) * E + h * HD + d4;

  const int Wl_[3] = {100, 50, 25};
  const int loff_[3] = {0, 10000, 12500};

  float4 acc = make_float4(0.f, 0.f, 0.f, 0.f);
#pragma unroll
  for (int l = 0; l < NL; ++l) {
    const int Wl = Wl_[l];
    const float* vl = vb + (size_t)loff_[l] * E;
#pragma unroll
    for (int p = 0; p < NP; ++p) {
      const float x = xy[l * 8 + p * 2 + 0];
      const float y = xy[l * 8 + p * 2 + 1];
      const float w = aw[l * 4 + p];
      const float fx = floorf(x), fy = floorf(y);
      const int x0 = (int)fx, y0 = (int)fy;
      const float wx1 = x - fx, wy1 = y - fy;
      const float wx0 = 1.f - wx1, wy0 = 1.f - wy1;

      const int x0c = min(max(x0, 0), Wl - 1);
      const int x1c = min(max(x0 + 1, 0), Wl - 1);
      const int y0c = min(max(y0, 0), Wl - 1);
      const int y1c = min(max(y0 + 1, 0), Wl - 1);
      const float vx0 = (x0 >= 0 && x0 < Wl) ? wx0 : 0.f;
      const float vx1 = (x0 + 1 >= 0 && x0 + 1 < Wl) ? wx1 : 0.f;
      const float vy0 = (y0 >= 0 && y0 < Wl) ? wy0 : 0.f;
      const float vy1 = (y0 + 1 >= 0 && y0 + 1 < Wl) ? wy1 : 0.f;

      const float4 c00 = *(const float4*)&vl[(size_t)(y0c * Wl + x0c) * E];
      const float4 c01 = *(const float4*)&vl[(size_t)(y0c * Wl + x1c) * E];
      const float4 c10 = *(const float4*)&vl[(size_t)(y1c * Wl + x0c) * E];
      const float4 c11 = *(const float4*)&vl[(size_t)(y1c * Wl + x1c) * E];

      const float w00 = w * vy0 * vx0, w01 = w * vy0 * vx1;
      const float w10 = w * vy1 * vx0, w11 = w * vy1 * vx1;
      acc.x += w00 * c00.x + w01 * c01.x + w10 * c10.x + w11 * c11.x;
      acc.y += w00 * c00.y + w01 * c01.y + w10 * c10.y + w11 * c11.y;
      acc.z += w00 * c00.z + w01 * c01.z + w10 * c10.z + w11 * c11.z;
      acc.w += w00 * c00.w + w01 * c01.w + w10 * c10.w + w11 * c11.w;
    }
  }
  *(float4*)&mid[(size_t)g * E + h * HD + d4] = acc;
}

// ---------------------------------------------------------------------------
extern "C" void kernel_launch(void* const* d_in, const int* in_sizes, int n_in,
                              void* d_out, int out_size, void* d_ws, size_t ws_size,
                              hipStream_t stream) {
  const float* query = (const float*)d_in[0];
  const float* refpt = (const float*)d_in[1];
  const float* value = (const float*)d_in[2];
  // d_in[3] = value_spatial_shapes (static, hardcoded)
  const float* Wv   = (const float*)d_in[4];
  const float* bv   = (const float*)d_in[5];
  const float* Woff = (const float*)d_in[6];
  const float* boff = (const float*)d_in[7];
  const float* Watt = (const float*)d_in[8];
  const float* batt = (const float*)d_in[9];
  const float* Wo   = (const float*)d_in[10];
  const float* bo   = (const float*)d_in[11];

  const int M = in_sizes[0] / E;  // B * Lq = 52500

  float* ws = (float*)d_ws;
  float* v      = ws;                       // M*256 floats
  float* sampXY = v + (size_t)M * E;        // M*192
  float* sampW  = sampXY + (size_t)M * 192; // M*96
  float* mid    = (float*)d_out;            // in-place with output

  const int rowBlocks = (M + 15) / 16;

  // 1. value projection -> v
  gemm256<<<rowBlocks, 256, 0, stream>>>(value, Wv, bv, v, M);
  // 2. sampling locations + softmax weights
  offatt<<<rowBlocks, 256, 0, stream>>>(query, refpt, Woff, boff, Watt, batt,
                                        sampXY, sampW, M);
  // 3. deformable bilinear sampling -> mid (= d_out)
  deform_sample4<<<(M * NH + 31) / 32, 256, 0, stream>>>(v, sampXY, sampW, mid, M);
  // 4. output projection, in-place on d_out
  gemm256<<<rowBlocks, 256, 0, stream>>>(mid, Wo, bo, (float*)d_out, M);
}

// Round 3
// 420.344 us; speedup vs baseline: 2.4227x; 1.6673x over previous
//
#include <hip/hip_runtime.h>
#include <hip/hip_bf16.h>

// Problem constants (fixed by the reference)
#define E    256
#define NH   8
#define NL   3
#define NP   4
#define HD   32
#define LQ   13125   // = Lv = 10000 + 2500 + 625

typedef short bf16x8 __attribute__((ext_vector_type(8)));
typedef float f32x4  __attribute__((ext_vector_type(4)));

// round-to-nearest-even fp32 -> bf16 (as ushort bits)
__device__ __forceinline__ ushort f2bf(float x) {
  uint u = __float_as_uint(x);
  uint r = (u + 0x7fffu + ((u >> 16) & 1u)) >> 16;
  return (ushort)r;
}
__device__ __forceinline__ float bf2f(ushort u) {
  return __uint_as_float((uint)u << 16);
}

// LDS tile swizzle: tile is [128 rows][32 k] bf16 (64B per row).
// byte addr = row*64 + byteoff, XOR bits 4-6 with row bits 0-2 so that
// ds_read_b128 fragment reads (16 rows x same 16B slot) spread across all
// eight 16B slot-groups (2 lanes/bank-group = conflict-free per m136).
__device__ __forceinline__ uint swz(uint row, uint byteoff) {
  return ((row << 6) + byteoff) ^ ((row & 7u) << 4);
}

// ---------------------------------------------------------------------------
// Split-bf16 MFMA GEMM: C[M,N] = A[M,256] @ B[256,N] + bias, fp32 in/out.
// B passed pre-transposed+pre-split: BTh/BTl are [N][256] bf16 (hi/lo).
// A is converted to hi/lo bf16 on the fly during LDS staging.
// acc = Ah*Bh + Ah*Bl + Al*Bh  (lo*lo dropped, ~2^-18 relative)
// Block: 256 threads = 4 waves (2x2), tile 128x128, BK=32, K=256.
// ---------------------------------------------------------------------------
__global__ __launch_bounds__(256) void gemm_mfma_split(
    const float* __restrict__ A, const ushort* __restrict__ BTh,
    const ushort* __restrict__ BTl, const float* __restrict__ bias,
    float* __restrict__ C, int M, int N) {
  __shared__ ushort Ah[4096], Al[4096], Bh[4096], Bl[4096];
  const int tid = threadIdx.x;
  const int lane = tid & 63;
  const int wid = tid >> 6;
  const int wm = wid >> 1, wn = wid & 1;
  const int r0 = blockIdx.x * 128;
  const int c0 = blockIdx.y * 128;
  const int l15 = lane & 15;
  const int lhi = lane >> 4;

  f32x4 acc[4][4] = {};

  for (int kc = 0; kc < 256; kc += 32) {
    // stage A: 128 rows x 32 k fp32 -> bf16 hi/lo
#pragma unroll
    for (int i = 0; i < 4; ++i) {
      const int flat = i * 1024 + tid * 4;
      const int row = flat >> 5, k = flat & 31;
      const int gr = r0 + row;
      float4 a = (gr < M) ? *(const float4*)&A[(size_t)gr * 256 + kc + k]
                          : make_float4(0.f, 0.f, 0.f, 0.f);
      ushort4 h, l;
      h.x = f2bf(a.x); l.x = f2bf(a.x - bf2f(h.x));
      h.y = f2bf(a.y); l.y = f2bf(a.y - bf2f(h.y));
      h.z = f2bf(a.z); l.z = f2bf(a.z - bf2f(h.z));
      h.w = f2bf(a.w); l.w = f2bf(a.w - bf2f(h.w));
      *(ushort4*)((char*)Ah + swz(row, k * 2)) = h;
      *(ushort4*)((char*)Al + swz(row, k * 2)) = l;
    }
    // stage B: 128 cols x 32 k bf16 hi/lo (already split, [n][k] layout)
#pragma unroll
    for (int i = 0; i < 4; ++i) {
      const int flat = i * 1024 + tid * 4;
      const int n = flat >> 5, k = flat & 31;
      const int gn = c0 + n;
      ushort4 h = make_ushort4(0, 0, 0, 0), l = make_ushort4(0, 0, 0, 0);
      if (gn < N) {
        h = *(const ushort4*)&BTh[(size_t)gn * 256 + kc + k];
        l = *(const ushort4*)&BTl[(size_t)gn * 256 + kc + k];
      }
      *(ushort4*)((char*)Bh + swz(n, k * 2)) = h;
      *(ushort4*)((char*)Bl + swz(n, k * 2)) = l;
    }
    __syncthreads();

    bf16x8 afh[4], afl[4], bfh[4], bfl[4];
#pragma unroll
    for (int mi = 0; mi < 4; ++mi) {
      const int row = wm * 64 + mi * 16 + l15;
      afh[mi] = *(const bf16x8*)((char*)Ah + swz(row, lhi * 16));
      afl[mi] = *(const bf16x8*)((char*)Al + swz(row, lhi * 16));
    }
#pragma unroll
    for (int ni = 0; ni < 4; ++ni) {
      const int col = wn * 64 + ni * 16 + l15;
      bfh[ni] = *(const bf16x8*)((char*)Bh + swz(col, lhi * 16));
      bfl[ni] = *(const bf16x8*)((char*)Bl + swz(col, lhi * 16));
    }
#pragma unroll
    for (int mi = 0; mi < 4; ++mi)
#pragma unroll
      for (int ni = 0; ni < 4; ++ni) {
        acc[mi][ni] = __builtin_amdgcn_mfma_f32_16x16x32_bf16(
            afl[mi], bfh[ni], acc[mi][ni], 0, 0, 0);
        acc[mi][ni] = __builtin_amdgcn_mfma_f32_16x16x32_bf16(
            afh[mi], bfl[ni], acc[mi][ni], 0, 0, 0);
        acc[mi][ni] = __builtin_amdgcn_mfma_f32_16x16x32_bf16(
            afh[mi], bfh[ni], acc[mi][ni], 0, 0, 0);
      }
    __syncthreads();
  }

  // epilogue: C/D layout col=lane&15, row=(lane>>4)*4+reg (m89-verified)
#pragma unroll
  for (int ni = 0; ni < 4; ++ni) {
    const int col = c0 + wn * 64 + ni * 16 + l15;
    if (col >= N) continue;
    const float b = bias[col];
#pragma unroll
    for (int mi = 0; mi < 4; ++mi) {
      const int rowb = r0 + wm * 64 + mi * 16 + lhi * 4;
#pragma unroll
      for (int r = 0; r < 4; ++r) {
        const int row = rowb + r;
        if (row < M) C[(size_t)row * N + col] = acc[mi][ni][r] + b;
      }
    }
  }
}

// ---------------------------------------------------------------------------
// One-shot weight prep: transpose + bf16 hi/lo split.
//  WvT/WoT: [256][256];  WcT: [288][256] = [Woff cols | Watt cols]; bias288.
// ---------------------------------------------------------------------------
__global__ __launch_bounds__(256) void convert_W(
    const float* __restrict__ Wv, const float* __restrict__ Woff,
    const float* __restrict__ Watt, const float* __restrict__ Wo,
    const float* __restrict__ boff, const float* __restrict__ batt,
    ushort* __restrict__ WvTh, ushort* __restrict__ WvTl,
    ushort* __restrict__ WcTh, ushort* __restrict__ WcTl,
    ushort* __restrict__ WoTh, ushort* __restrict__ WoTl,
    float* __restrict__ bias288) {
  const int t = blockIdx.x * 256 + threadIdx.x;
  if (t < 256 * 256) {
    const int n = t >> 8, k = t & 255;
    float v = Wv[k * 256 + n];
    ushort h = f2bf(v);
    WvTh[t] = h; WvTl[t] = f2bf(v - bf2f(h));
    float o = Wo[k * 256 + n];
    h = f2bf(o);
    WoTh[t] = h; WoTl[t] = f2bf(o - bf2f(h));
  }
  if (t < 288 * 256) {
    const int n = t >> 8, k = t & 255;
    const float w = (n < 192) ? Woff[k * 192 + n] : Watt[k * 96 + (n - 192)];
    const ushort h = f2bf(w);
    WcTh[t] = h; WcTl[t] = f2bf(w - bf2f(h));
  }
  if (t < 288) bias288[t] = (t < 192) ? boff[t] : batt[t - 192];
}

// ---------------------------------------------------------------------------
// Finalize raw projection [M][288] in place:
//  cols 0..191  -> pixel coords: ref*S + raw - 0.5
//  cols 192..287 -> softmax over each head's 12 (l,p) values
// 16 rows per block; coord threads and softmax threads touch disjoint cols.
// ---------------------------------------------------------------------------
__global__ __launch_bounds__(256) void finalize(
    float* __restrict__ raw, const float* __restrict__ ref, int M) {
  const int tid = threadIdx.x;
  const int g0 = blockIdx.x * 16;
  const float S_[3] = {100.f, 50.f, 25.f};

  for (int idx = tid; idx < 16 * 192; idx += 256) {
    const int r = idx / 192, col = idx - r * 192;
    const int g = g0 + r;
    if (g >= M) break;
    const int l = (col % 24) >> 3;
    const int xy = col & 1;
    raw[(size_t)g * 288 + col] =
        ref[(size_t)g * 6 + l * 2 + xy] * S_[l] + raw[(size_t)g * 288 + col] - 0.5f;
  }
  if (tid < 128) {
    const int r = tid >> 3, h = tid & 7;
    const int g = g0 + r;
    if (g < M) {
      float* a = raw + (size_t)g * 288 + 192 + h * 12;
      float m = a[0];
#pragma unroll
      for (int j = 1; j < 12; ++j) m = fmaxf(m, a[j]);
      float e[12], s = 0.f;
#pragma unroll
      for (int j = 0; j < 12; ++j) { e[j] = expf(a[j] - m); s += e[j]; }
      const float inv = 1.f / s;
#pragma unroll
      for (int j = 0; j < 12; ++j) a[j] = e[j] * inv;
    }
  }
}

// ---------------------------------------------------------------------------
// Bilinear sampling + attention-weighted accumulation, float4 version.
// 8 lanes per (g, h) group; lane owns 4 channels.  raw layout: [g][288] with
// coords at [g][h*24..] and softmax weights at [g][192 + h*12..].
// ---------------------------------------------------------------------------
__global__ __launch_bounds__(256) void deform_sample4(
    const float* __restrict__ v, const float* __restrict__ raw,
    float* __restrict__ mid, int M) {
  const int tid = threadIdx.x;
  const int gidx = blockIdx.x * 32 + (tid >> 3);
  if (gidx >= M * NH) return;
  const int d4 = (tid & 7) << 2;
  const int g = gidx >> 3;
  const int h = gidx & 7;
  const int b = g / LQ;

  const float4* xy4 = (const float4*)(raw + (size_t)g * 288 + h * 24);
  const float4* aw4 = (const float4*)(raw + (size_t)g * 288 + 192 + h * 12);
  float xy[24], aw[12];
#pragma unroll
  for (int i = 0; i < 6; ++i) {
    float4 t = xy4[i];
    xy[4 * i + 0] = t.x; xy[4 * i + 1] = t.y;
    xy[4 * i + 2] = t.z; xy[4 * i + 3] = t.w;
  }
#pragma unroll
  for (int i = 0; i < 3; ++i) {
    float4 t = aw4[i];
    aw[4 * i + 0] = t.x; aw[4 * i + 1] = t.y;
    aw[4 * i + 2] = t.z; aw[4 * i + 3] = t.w;
  }

  const float* vb = v + ((size_t)b * LQ) * E + h * HD + d4;

  const int Wl_[3] = {100, 50, 25};
  const int loff_[3] = {0, 10000, 12500};

  float4 acc = make_float4(0.f, 0.f, 0.f, 0.f);
#pragma unroll
  for (int l = 0; l < NL; ++l) {
    const int Wl = Wl_[l];
    const float* vl = vb + (size_t)loff_[l] * E;
#pragma unroll
    for (int p = 0; p < NP; ++p) {
      const float x = xy[l * 8 + p * 2 + 0];
      const float y = xy[l * 8 + p * 2 + 1];
      const float w = aw[l * 4 + p];
      const float fx = floorf(x), fy = floorf(y);
      const int x0 = (int)fx, y0 = (int)fy;
      const float wx1 = x - fx, wy1 = y - fy;
      const float wx0 = 1.f - wx1, wy0 = 1.f - wy1;

      const int x0c = min(max(x0, 0), Wl - 1);
      const int x1c = min(max(x0 + 1, 0), Wl - 1);
      const int y0c = min(max(y0, 0), Wl - 1);
      const int y1c = min(max(y0 + 1, 0), Wl - 1);
      const float vx0 = (x0 >= 0 && x0 < Wl) ? wx0 : 0.f;
      const float vx1 = (x0 + 1 >= 0 && x0 + 1 < Wl) ? wx1 : 0.f;
      const float vy0 = (y0 >= 0 && y0 < Wl) ? wy0 : 0.f;
      const float vy1 = (y0 + 1 >= 0 && y0 + 1 < Wl) ? wy1 : 0.f;

      const float4 c00 = *(const float4*)&vl[(size_t)(y0c * Wl + x0c) * E];
      const float4 c01 = *(const float4*)&vl[(size_t)(y0c * Wl + x1c) * E];
      const float4 c10 = *(const float4*)&vl[(size_t)(y1c * Wl + x0c) * E];
      const float4 c11 = *(const float4*)&vl[(size_t)(y1c * Wl + x1c) * E];

      const float w00 = w * vy0 * vx0, w01 = w * vy0 * vx1;
      const float w10 = w * vy1 * vx0, w11 = w * vy1 * vx1;
      acc.x += w00 * c00.x + w01 * c01.x + w10 * c10.x + w11 * c11.x;
      acc.y += w00 * c00.y + w01 * c01.y + w10 * c10.y + w11 * c11.y;
      acc.z += w00 * c00.z + w01 * c01.z + w10 * c10.z + w11 * c11.z;
      acc.w += w00 * c00.w + w01 * c01.w + w10 * c10.w + w11 * c11.w;
    }
  }
  *(float4*)&mid[(size_t)g * E + h * HD + d4] = acc;
}

// ---------------------------------------------------------------------------
extern "C" void kernel_launch(void* const* d_in, const int* in_sizes, int n_in,
                              void* d_out, int out_size, void* d_ws, size_t ws_size,
                              hipStream_t stream) {
  const float* query = (const float*)d_in[0];
  const float* refpt = (const float*)d_in[1];
  const float* value = (const float*)d_in[2];
  // d_in[3] = value_spatial_shapes (static, hardcoded)
  const float* Wv   = (const float*)d_in[4];
  const float* bv   = (const float*)d_in[5];
  const float* Woff = (const float*)d_in[6];
  const float* boff = (const float*)d_in[7];
  const float* Watt = (const float*)d_in[8];
  const float* batt = (const float*)d_in[9];
  const float* Wo   = (const float*)d_in[10];
  const float* bo   = (const float*)d_in[11];

  const int M = in_sizes[0] / E;  // B * Lq = 52500

  // workspace layout
  float* wsf  = (float*)d_ws;
  float* raw  = wsf;                         // M*288
  float* mid  = raw + (size_t)M * 288;       // M*256
  float* b288 = mid + (size_t)M * 256;       // 288
  ushort* wvh = (ushort*)(b288 + 288);       // 65536 each
  ushort* wvl = wvh + 65536;
  ushort* woh = wvl + 65536;
  ushort* wol = woh + 65536;
  ushort* wch = wol + 65536;                 // 73728 each
  ushort* wcl = wch + 73728;
  float* v    = (float*)d_out;               // value projection lives in d_out

  const int gridM = (M + 127) / 128;

  // 0. weight prep (transpose + hi/lo split)
  convert_W<<<288, 256, 0, stream>>>(Wv, Woff, Watt, Wo, boff, batt,
                                     wvh, wvl, wch, wcl, woh, wol, b288);
  // 1. value projection -> v (in d_out; A=value, so no aliasing)
  gemm_mfma_split<<<dim3(gridM, 2), 256, 0, stream>>>(value, wvh, wvl, bv, v, M, 256);
  // 2. offsets+attention raw projection -> raw
  gemm_mfma_split<<<dim3(gridM, 3), 256, 0, stream>>>(query, wch, wcl, b288, raw, M, 288);
  // 3. coords + softmax, in place on raw
  finalize<<<(M + 15) / 16, 256, 0, stream>>>(raw, refpt, M);
  // 4. deformable bilinear sampling: reads v (d_out), writes mid (ws)
  deform_sample4<<<(M * NH + 31) / 32, 256, 0, stream>>>(v, raw, mid, M);
  // 5. output projection: reads mid (ws), overwrites d_out (v is dead)
  gemm_mfma_split<<<dim3(gridM, 2), 256, 0, stream>>>(mid, woh, wol, bo, (float*)d_out, M, 256);
}

// Round 4
// 352.312 us; speedup vs baseline: 2.8905x; 1.1931x over previous
//
#include <hip/hip_runtime.h>
#include <hip/hip_bf16.h>

// Problem constants (fixed by the reference)
#define E    256
#define NH   8
#define NL   3
#define NP   4
#define HD   32
#define LQ   13125   // = Lv = 10000 + 2500 + 625

typedef short bf16x8 __attribute__((ext_vector_type(8)));
typedef float f32x4  __attribute__((ext_vector_type(4)));

// round-to-nearest-even fp32 -> bf16 (as ushort bits)
__device__ __forceinline__ ushort f2bf(float x) {
  uint u = __float_as_uint(x);
  uint r = (u + 0x7fffu + ((u >> 16) & 1u)) >> 16;
  return (ushort)r;
}
__device__ __forceinline__ float bf2f(ushort u) {
  return __uint_as_float((uint)u << 16);
}

// LDS tile swizzle: tile is [128 rows][32 k] bf16 (64B per row).
__device__ __forceinline__ uint swz(uint row, uint byteoff) {
  return ((row << 6) + byteoff) ^ ((row & 7u) << 4);
}

// ---------------------------------------------------------------------------
// Split-bf16 MFMA GEMM: C[M,N] = A[M,256] @ B[256,N] + bias, fp32 in.
// OUT_MODE 0: fp32 C[M][N].  OUT_MODE 1: bf16 head-major value layout
//   vbf[((b*8 + col>>5)*LQ + pos)*32 + (col&31)],  b=row/LQ, pos=row%LQ.
// acc = Ah*Bh + Ah*Bl + Al*Bh  (lo*lo dropped)
// ---------------------------------------------------------------------------
template <int OUT_MODE>
__global__ __launch_bounds__(256) void gemm_mfma_split(
    const float* __restrict__ A, const ushort* __restrict__ BTh,
    const ushort* __restrict__ BTl, const float* __restrict__ bias,
    float* __restrict__ C, ushort* __restrict__ Cbf, int M, int N) {
  __shared__ ushort Ah[4096], Al[4096], Bh[4096], Bl[4096];
  const int tid = threadIdx.x;
  const int lane = tid & 63;
  const int wid = tid >> 6;
  const int wm = wid >> 1, wn = wid & 1;
  const int r0 = blockIdx.x * 128;
  const int c0 = blockIdx.y * 128;
  const int l15 = lane & 15;
  const int lhi = lane >> 4;

  f32x4 acc[4][4] = {};

  for (int kc = 0; kc < 256; kc += 32) {
#pragma unroll
    for (int i = 0; i < 4; ++i) {
      const int flat = i * 1024 + tid * 4;
      const int row = flat >> 5, k = flat & 31;
      const int gr = r0 + row;
      float4 a = (gr < M) ? *(const float4*)&A[(size_t)gr * 256 + kc + k]
                          : make_float4(0.f, 0.f, 0.f, 0.f);
      ushort4 h, l;
      h.x = f2bf(a.x); l.x = f2bf(a.x - bf2f(h.x));
      h.y = f2bf(a.y); l.y = f2bf(a.y - bf2f(h.y));
      h.z = f2bf(a.z); l.z = f2bf(a.z - bf2f(h.z));
      h.w = f2bf(a.w); l.w = f2bf(a.w - bf2f(h.w));
      *(ushort4*)((char*)Ah + swz(row, k * 2)) = h;
      *(ushort4*)((char*)Al + swz(row, k * 2)) = l;
    }
#pragma unroll
    for (int i = 0; i < 4; ++i) {
      const int flat = i * 1024 + tid * 4;
      const int n = flat >> 5, k = flat & 31;
      const int gn = c0 + n;
      ushort4 h = make_ushort4(0, 0, 0, 0), l = make_ushort4(0, 0, 0, 0);
      if (gn < N) {
        h = *(const ushort4*)&BTh[(size_t)gn * 256 + kc + k];
        l = *(const ushort4*)&BTl[(size_t)gn * 256 + kc + k];
      }
      *(ushort4*)((char*)Bh + swz(n, k * 2)) = h;
      *(ushort4*)((char*)Bl + swz(n, k * 2)) = l;
    }
    __syncthreads();

    bf16x8 afh[4], afl[4], bfh[4], bfl[4];
#pragma unroll
    for (int mi = 0; mi < 4; ++mi) {
      const int row = wm * 64 + mi * 16 + l15;
      afh[mi] = *(const bf16x8*)((char*)Ah + swz(row, lhi * 16));
      afl[mi] = *(const bf16x8*)((char*)Al + swz(row, lhi * 16));
    }
#pragma unroll
    for (int ni = 0; ni < 4; ++ni) {
      const int col = wn * 64 + ni * 16 + l15;
      bfh[ni] = *(const bf16x8*)((char*)Bh + swz(col, lhi * 16));
      bfl[ni] = *(const bf16x8*)((char*)Bl + swz(col, lhi * 16));
    }
#pragma unroll
    for (int mi = 0; mi < 4; ++mi)
#pragma unroll
      for (int ni = 0; ni < 4; ++ni) {
        acc[mi][ni] = __builtin_amdgcn_mfma_f32_16x16x32_bf16(
            afl[mi], bfh[ni], acc[mi][ni], 0, 0, 0);
        acc[mi][ni] = __builtin_amdgcn_mfma_f32_16x16x32_bf16(
            afh[mi], bfl[ni], acc[mi][ni], 0, 0, 0);
        acc[mi][ni] = __builtin_amdgcn_mfma_f32_16x16x32_bf16(
            afh[mi], bfh[ni], acc[mi][ni], 0, 0, 0);
      }
    __syncthreads();
  }

  // epilogue: C/D layout col=lane&15, row=(lane>>4)*4+reg
#pragma unroll
  for (int ni = 0; ni < 4; ++ni) {
    const int col = c0 + wn * 64 + ni * 16 + l15;
    if (col >= N) continue;
    const float bb = bias[col];
#pragma unroll
    for (int mi = 0; mi < 4; ++mi) {
      const int rowb = r0 + wm * 64 + mi * 16 + lhi * 4;
#pragma unroll
      for (int r = 0; r < 4; ++r) {
        const int row = rowb + r;
        if (row >= M) continue;
        if (OUT_MODE == 0) {
          C[(size_t)row * N + col] = acc[mi][ni][r] + bb;
        } else {
          const int bidx = row / LQ, pos = row - bidx * LQ;
          const int h = col >> 5, d = col & 31;
          Cbf[((size_t)(bidx * NH + h) * LQ + pos) * HD + d] =
              f2bf(acc[mi][ni][r] + bb);
        }
      }
    }
  }
}

// ---------------------------------------------------------------------------
// bf16-A MFMA GEMM: C[M,N] = A_bf16[M,256] @ B + bias (B split hi/lo).
// acc = Ah*Bh + Ah*Bl  (A has no lo part; 2 MFMAs per tile).
// ---------------------------------------------------------------------------
__global__ __launch_bounds__(256) void gemm_mfma_bf16A(
    const ushort* __restrict__ A, const ushort* __restrict__ BTh,
    const ushort* __restrict__ BTl, const float* __restrict__ bias,
    float* __restrict__ C, int M, int N) {
  __shared__ ushort Ah[4096], Bh[4096], Bl[4096];
  const int tid = threadIdx.x;
  const int lane = tid & 63;
  const int wid = tid >> 6;
  const int wm = wid >> 1, wn = wid & 1;
  const int r0 = blockIdx.x * 128;
  const int c0 = blockIdx.y * 128;
  const int l15 = lane & 15;
  const int lhi = lane >> 4;

  f32x4 acc[4][4] = {};

  for (int kc = 0; kc < 256; kc += 32) {
#pragma unroll
    for (int i = 0; i < 2; ++i) {
      const int flat = i * 2048 + tid * 8;
      const int row = flat >> 5, k = flat & 31;
      const int gr = r0 + row;
      bf16x8 a = {};
      if (gr < M) a = *(const bf16x8*)&A[(size_t)gr * 256 + kc + k];
      *(bf16x8*)((char*)Ah + swz(row, k * 2)) = a;
    }
#pragma unroll
    for (int i = 0; i < 4; ++i) {
      const int flat = i * 1024 + tid * 4;
      const int n = flat >> 5, k = flat & 31;
      const int gn = c0 + n;
      ushort4 h = make_ushort4(0, 0, 0, 0), l = make_ushort4(0, 0, 0, 0);
      if (gn < N) {
        h = *(const ushort4*)&BTh[(size_t)gn * 256 + kc + k];
        l = *(const ushort4*)&BTl[(size_t)gn * 256 + kc + k];
      }
      *(ushort4*)((char*)Bh + swz(n, k * 2)) = h;
      *(ushort4*)((char*)Bl + swz(n, k * 2)) = l;
    }
    __syncthreads();

    bf16x8 afh[4], bfh[4], bfl[4];
#pragma unroll
    for (int mi = 0; mi < 4; ++mi) {
      const int row = wm * 64 + mi * 16 + l15;
      afh[mi] = *(const bf16x8*)((char*)Ah + swz(row, lhi * 16));
    }
#pragma unroll
    for (int ni = 0; ni < 4; ++ni) {
      const int col = wn * 64 + ni * 16 + l15;
      bfh[ni] = *(const bf16x8*)((char*)Bh + swz(col, lhi * 16));
      bfl[ni] = *(const bf16x8*)((char*)Bl + swz(col, lhi * 16));
    }
#pragma unroll
    for (int mi = 0; mi < 4; ++mi)
#pragma unroll
      for (int ni = 0; ni < 4; ++ni) {
        acc[mi][ni] = __builtin_amdgcn_mfma_f32_16x16x32_bf16(
            afh[mi], bfl[ni], acc[mi][ni], 0, 0, 0);
        acc[mi][ni] = __builtin_amdgcn_mfma_f32_16x16x32_bf16(
            afh[mi], bfh[ni], acc[mi][ni], 0, 0, 0);
      }
    __syncthreads();
  }

#pragma unroll
  for (int ni = 0; ni < 4; ++ni) {
    const int col = c0 + wn * 64 + ni * 16 + l15;
    if (col >= N) continue;
    const float bb = bias[col];
#pragma unroll
    for (int mi = 0; mi < 4; ++mi) {
      const int rowb = r0 + wm * 64 + mi * 16 + lhi * 4;
#pragma unroll
      for (int r = 0; r < 4; ++r) {
        const int row = rowb + r;
        if (row < M) C[(size_t)row * N + col] = acc[mi][ni][r] + bb;
      }
    }
  }
}

// ---------------------------------------------------------------------------
// One-shot weight prep: transpose + bf16 hi/lo split.
// ---------------------------------------------------------------------------
__global__ __launch_bounds__(256) void convert_W(
    const float* __restrict__ Wv, const float* __restrict__ Woff,
    const float* __restrict__ Watt, const float* __restrict__ Wo,
    const float* __restrict__ boff, const float* __restrict__ batt,
    ushort* __restrict__ WvTh, ushort* __restrict__ WvTl,
    ushort* __restrict__ WcTh, ushort* __restrict__ WcTl,
    ushort* __restrict__ WoTh, ushort* __restrict__ WoTl,
    float* __restrict__ bias288) {
  const int t = blockIdx.x * 256 + threadIdx.x;
  if (t < 256 * 256) {
    const int n = t >> 8, k = t & 255;
    float v = Wv[k * 256 + n];
    ushort h = f2bf(v);
    WvTh[t] = h; WvTl[t] = f2bf(v - bf2f(h));
    float o = Wo[k * 256 + n];
    h = f2bf(o);
    WoTh[t] = h; WoTl[t] = f2bf(o - bf2f(h));
  }
  if (t < 288 * 256) {
    const int n = t >> 8, k = t & 255;
    const float w = (n < 192) ? Woff[k * 192 + n] : Watt[k * 96 + (n - 192)];
    const ushort h = f2bf(w);
    WcTh[t] = h; WcTl[t] = f2bf(w - bf2f(h));
  }
  if (t < 288) bias288[t] = (t < 192) ? boff[t] : batt[t - 192];
}

// ---------------------------------------------------------------------------
// Finalize raw projection [M][288] in place: coords + softmax.
// ---------------------------------------------------------------------------
__global__ __launch_bounds__(256) void finalize(
    float* __restrict__ raw, const float* __restrict__ ref, int M) {
  const int tid = threadIdx.x;
  const int g0 = blockIdx.x * 16;
  const float S_[3] = {100.f, 50.f, 25.f};

  for (int idx = tid; idx < 16 * 192; idx += 256) {
    const int r = idx / 192, col = idx - r * 192;
    const int g = g0 + r;
    if (g >= M) break;
    const int l = (col % 24) >> 3;
    const int xy = col & 1;
    raw[(size_t)g * 288 + col] =
        ref[(size_t)g * 6 + l * 2 + xy] * S_[l] + raw[(size_t)g * 288 + col] - 0.5f;
  }
  if (tid < 128) {
    const int r = tid >> 3, h = tid & 7;
    const int g = g0 + r;
    if (g < M) {
      float* a = raw + (size_t)g * 288 + 192 + h * 12;
      float m = a[0];
#pragma unroll
      for (int j = 1; j < 12; ++j) m = fmaxf(m, a[j]);
      float e[12], s = 0.f;
#pragma unroll
      for (int j = 0; j < 12; ++j) { e[j] = expf(a[j] - m); s += e[j]; }
      const float inv = 1.f / s;
#pragma unroll
      for (int j = 0; j < 12; ++j) a[j] = e[j] * inv;
    }
  }
}

// ---------------------------------------------------------------------------
// Bilinear sampling, bf16 value.  vbf layout: [(b*8+h)][pos][32] bf16
// (64B per position slice).  8 lanes per (g,h) group; lane owns 4 channels
// (ushort4 = 8B per corner load).  Output mid: bf16 [g][256].
// ---------------------------------------------------------------------------
__global__ __launch_bounds__(256) void deform_sample_bf16(
    const ushort* __restrict__ vbf, const float* __restrict__ raw,
    ushort* __restrict__ mid, int M) {
  const int tid = threadIdx.x;
  const int gidx = blockIdx.x * 32 + (tid >> 3);
  if (gidx >= M * NH) return;
  const int d4 = (tid & 7) << 2;
  const int g = gidx >> 3;
  const int h = gidx & 7;
  const int b = g / LQ;

  const float4* xy4 = (const float4*)(raw + (size_t)g * 288 + h * 24);
  const float4* aw4 = (const float4*)(raw + (size_t)g * 288 + 192 + h * 12);
  float xy[24], aw[12];
#pragma unroll
  for (int i = 0; i < 6; ++i) {
    float4 t = xy4[i];
    xy[4 * i + 0] = t.x; xy[4 * i + 1] = t.y;
    xy[4 * i + 2] = t.z; xy[4 * i + 3] = t.w;
  }
#pragma unroll
  for (int i = 0; i < 3; ++i) {
    float4 t = aw4[i];
    aw[4 * i + 0] = t.x; aw[4 * i + 1] = t.y;
    aw[4 * i + 2] = t.z; aw[4 * i + 3] = t.w;
  }

  const ushort* vb = vbf + ((size_t)(b * NH + h) * LQ) * HD + d4;

  const int Wl_[3] = {100, 50, 25};
  const int loff_[3] = {0, 10000, 12500};

  float4 acc = make_float4(0.f, 0.f, 0.f, 0.f);
#pragma unroll
  for (int l = 0; l < NL; ++l) {
    const int Wl = Wl_[l];
    const ushort* vl = vb + (size_t)loff_[l] * HD;
#pragma unroll
    for (int p = 0; p < NP; ++p) {
      const float x = xy[l * 8 + p * 2 + 0];
      const float y = xy[l * 8 + p * 2 + 1];
      const float w = aw[l * 4 + p];
      const float fx = floorf(x), fy = floorf(y);
      const int x0 = (int)fx, y0 = (int)fy;
      const float wx1 = x - fx, wy1 = y - fy;
      const float wx0 = 1.f - wx1, wy0 = 1.f - wy1;

      const int x0c = min(max(x0, 0), Wl - 1);
      const int x1c = min(max(x0 + 1, 0), Wl - 1);
      const int y0c = min(max(y0, 0), Wl - 1);
      const int y1c = min(max(y0 + 1, 0), Wl - 1);
      const float vx0 = (x0 >= 0 && x0 < Wl) ? wx0 : 0.f;
      const float vx1 = (x0 + 1 >= 0 && x0 + 1 < Wl) ? wx1 : 0.f;
      const float vy0 = (y0 >= 0 && y0 < Wl) ? wy0 : 0.f;
      const float vy1 = (y0 + 1 >= 0 && y0 + 1 < Wl) ? wy1 : 0.f;

      const ushort4 c00 = *(const ushort4*)&vl[(size_t)(y0c * Wl + x0c) * HD];
      const ushort4 c01 = *(const ushort4*)&vl[(size_t)(y0c * Wl + x1c) * HD];
      const ushort4 c10 = *(const ushort4*)&vl[(size_t)(y1c * Wl + x0c) * HD];
      const ushort4 c11 = *(const ushort4*)&vl[(size_t)(y1c * Wl + x1c) * HD];

      const float w00 = w * vy0 * vx0, w01 = w * vy0 * vx1;
      const float w10 = w * vy1 * vx0, w11 = w * vy1 * vx1;
      acc.x += w00 * bf2f(c00.x) + w01 * bf2f(c01.x) + w10 * bf2f(c10.x) + w11 * bf2f(c11.x);
      acc.y += w00 * bf2f(c00.y) + w01 * bf2f(c01.y) + w10 * bf2f(c10.y) + w11 * bf2f(c11.y);
      acc.z += w00 * bf2f(c00.z) + w01 * bf2f(c01.z) + w10 * bf2f(c10.z) + w11 * bf2f(c11.z);
      acc.w += w00 * bf2f(c00.w) + w01 * bf2f(c01.w) + w10 * bf2f(c10.w) + w11 * bf2f(c11.w);
    }
  }
  ushort4 o;
  o.x = f2bf(acc.x); o.y = f2bf(acc.y); o.z = f2bf(acc.z); o.w = f2bf(acc.w);
  *(ushort4*)&mid[(size_t)g * E + h * HD + d4] = o;
}

// ---------------------------------------------------------------------------
extern "C" void kernel_launch(void* const* d_in, const int* in_sizes, int n_in,
                              void* d_out, int out_size, void* d_ws, size_t ws_size,
                              hipStream_t stream) {
  const float* query = (const float*)d_in[0];
  const float* refpt = (const float*)d_in[1];
  const float* value = (const float*)d_in[2];
  const float* Wv   = (const float*)d_in[4];
  const float* bv   = (const float*)d_in[5];
  const float* Woff = (const float*)d_in[6];
  const float* boff = (const float*)d_in[7];
  const float* Watt = (const float*)d_in[8];
  const float* batt = (const float*)d_in[9];
  const float* Wo   = (const float*)d_in[10];
  const float* bo   = (const float*)d_in[11];

  const int M = in_sizes[0] / E;  // B * Lq = 52500

  // workspace layout (~115 MB)
  float* wsf   = (float*)d_ws;
  float* raw   = wsf;                         // M*288 floats
  float* b288  = raw + (size_t)M * 288;       // 288
  ushort* mid  = (ushort*)(b288 + 288);       // M*256 ushorts
  ushort* vbf  = mid + (size_t)M * 256;       // M*256 ushorts
  ushort* wvh  = vbf + (size_t)M * 256;       // 65536 each
  ushort* wvl  = wvh + 65536;
  ushort* woh  = wvl + 65536;
  ushort* wol  = woh + 65536;
  ushort* wch  = wol + 65536;                 // 73728 each
  ushort* wcl  = wch + 73728;

  const int gridM = (M + 127) / 128;

  // 0. weight prep
  convert_W<<<288, 256, 0, stream>>>(Wv, Woff, Watt, Wo, boff, batt,
                                     wvh, wvl, wch, wcl, woh, wol, b288);
  // 1. value projection -> vbf (bf16, head-major)
  gemm_mfma_split<1><<<dim3(gridM, 2), 256, 0, stream>>>(
      value, wvh, wvl, bv, nullptr, vbf, M, 256);
  // 2. offsets+attention raw projection -> raw (fp32)
  gemm_mfma_split<0><<<dim3(gridM, 3), 256, 0, stream>>>(
      query, wch, wcl, b288, raw, nullptr, M, 288);
  // 3. coords + softmax, in place on raw
  finalize<<<(M + 15) / 16, 256, 0, stream>>>(raw, refpt, M);
  // 4. deformable bilinear sampling -> mid (bf16)
  deform_sample_bf16<<<(M * NH + 31) / 32, 256, 0, stream>>>(vbf, raw, mid, M);
  // 5. output projection: mid (bf16) -> d_out (fp32)
  gemm_mfma_bf16A<<<dim3(gridM, 2), 256, 0, stream>>>(
      mid, woh, wol, bo, (float*)d_out, M, 256);
}

// Round 5
// 334.596 us; speedup vs baseline: 3.0436x; 1.0529x over previous
//
#include <hip/hip_runtime.h>
#include <hip/hip_bf16.h>

// Problem constants (fixed by the reference)
#define E    256
#define NH   8
#define NL   3
#define NP   4
#define HD   32
#define LQ   13125   // = Lv = 10000 + 2500 + 625

typedef short bf16x8 __attribute__((ext_vector_type(8)));
typedef float f32x4  __attribute__((ext_vector_type(4)));

// round-to-nearest-even fp32 -> bf16 (as ushort bits)
__device__ __forceinline__ ushort f2bf(float x) {
  uint u = __float_as_uint(x);
  uint r = (u + 0x7fffu + ((u >> 16) & 1u)) >> 16;
  return (ushort)r;
}
__device__ __forceinline__ float bf2f(ushort u) {
  return __uint_as_float((uint)u << 16);
}

// ---------------------------------------------------------------------------
// fp32 [M][256] -> bf16 hi/lo [M][256] each (hi = rne(a), lo = rne(a - hi)).
// ---------------------------------------------------------------------------
__global__ __launch_bounds__(256) void convertA(
    const float* __restrict__ A, ushort* __restrict__ hi,
    ushort* __restrict__ lo, int n4) {
  const int i = blockIdx.x * 256 + threadIdx.x;
  if (i >= n4) return;
  const float4 a = ((const float4*)A)[i];
  ushort4 h, l;
  h.x = f2bf(a.x); l.x = f2bf(a.x - bf2f(h.x));
  h.y = f2bf(a.y); l.y = f2bf(a.y - bf2f(h.y));
  h.z = f2bf(a.z); l.z = f2bf(a.z - bf2f(h.z));
  h.w = f2bf(a.w); l.w = f2bf(a.w - bf2f(h.w));
  ((ushort4*)hi)[i] = h;
  ((ushort4*)lo)[i] = l;
}

// ---------------------------------------------------------------------------
// m97-structure bf16 MFMA GEMM with virtual-K phases (split-bf16 fp32 emu):
//   C = sum_ph  A[ph] @ B[ph]^T,  each phase a K=256 bf16 panel.
// A*: [M][256] bf16 row-major.  B*: [N][256] bf16 (transposed weights).
// Tile 128x128, 4 waves (2x2), BK=32, LDS linear [128][32] (16 KB total),
// staged via global_load_lds width-16 (dest = wave-uniform base + lane*16).
// OOB rows/cols: clamp the per-lane GLOBAL index (results masked at epilogue).
// OUT_MODE 0: fp32 C[M][N].  OUT_MODE 1: bf16 head-major value layout
//   Cbf[((b*8 + col>>5)*LQ + pos)*32 + (col&31)],  b=row/LQ, pos=row%LQ.
// ---------------------------------------------------------------------------
template <int NPH, int OUT_MODE>
__global__ __launch_bounds__(256) void gemm_gl(
    const ushort* __restrict__ A0, const ushort* __restrict__ A1,
    const ushort* __restrict__ A2,
    const ushort* __restrict__ B0, const ushort* __restrict__ B1,
    const ushort* __restrict__ B2,
    const float* __restrict__ bias, float* __restrict__ C,
    ushort* __restrict__ Cbf, int M, int N) {
  __shared__ ushort As[128 * 32];
  __shared__ ushort Bs[128 * 32];
  const int tid = threadIdx.x;
  const int lane = tid & 63;
  const int wid = tid >> 6;
  const int wm = wid >> 1, wn = wid & 1;
  const int r0 = blockIdx.x * 128;
  const int c0 = blockIdx.y * 128;
  const int l15 = lane & 15;
  const int lhi = lane >> 4;
  const int srow = lane >> 2;        // row within 16-row chunk
  const int skoff = (lane & 3) * 8;  // ushort offset within 32-elem row

  f32x4 acc[4][4] = {};

  const ushort* APH[3] = {A0, A1, A2};
  const ushort* BPH[3] = {B0, B1, B2};

#pragma unroll
  for (int ph = 0; ph < NPH; ++ph) {
    const ushort* Ap = APH[ph];
    const ushort* Bp = BPH[ph];
    for (int kk = 0; kk < 256; kk += 32) {
      // each wave fills LDS chunks {wid, wid+4} of A and B (1 KB each)
#pragma unroll
      for (int j = 0; j < 2; ++j) {
        const int c = wid + j * 4;
        const int arow = min(r0 + c * 16 + srow, M - 1);
        const int brow = min(c0 + c * 16 + srow, N - 1);
        __builtin_amdgcn_global_load_lds(
            (const __attribute__((address_space(1))) void*)(
                Ap + (size_t)arow * 256 + kk + skoff),
            (__attribute__((address_space(3))) void*)(As + c * 512), 16, 0, 0);
        __builtin_amdgcn_global_load_lds(
            (const __attribute__((address_space(1))) void*)(
                Bp + (size_t)brow * 256 + kk + skoff),
            (__attribute__((address_space(3))) void*)(Bs + c * 512), 16, 0, 0);
      }
      __syncthreads();  // drains vmcnt (global_load_lds) before LDS reads

      bf16x8 af[4], bf[4];
#pragma unroll
      for (int mi = 0; mi < 4; ++mi)
        af[mi] = *(const bf16x8*)&As[(wm * 64 + mi * 16 + l15) * 32 + lhi * 8];
#pragma unroll
      for (int ni = 0; ni < 4; ++ni)
        bf[ni] = *(const bf16x8*)&Bs[(wn * 64 + ni * 16 + l15) * 32 + lhi * 8];
#pragma unroll
      for (int mi = 0; mi < 4; ++mi)
#pragma unroll
        for (int ni = 0; ni < 4; ++ni)
          acc[mi][ni] = __builtin_amdgcn_mfma_f32_16x16x32_bf16(
              af[mi], bf[ni], acc[mi][ni], 0, 0, 0);
      __syncthreads();  // protect LDS from next-iteration staging
    }
  }

  // epilogue: C/D layout col=lane&15, row=(lane>>4)*4+reg (m89-verified)
#pragma unroll
  for (int ni = 0; ni < 4; ++ni) {
    const int col = c0 + wn * 64 + ni * 16 + l15;
    if (col >= N) continue;
    const float bb = bias[col];
#pragma unroll
    for (int mi = 0; mi < 4; ++mi) {
      const int rowb = r0 + wm * 64 + mi * 16 + lhi * 4;
#pragma unroll
      for (int r = 0; r < 4; ++r) {
        const int row = rowb + r;
        if (row >= M) continue;
        if (OUT_MODE == 0) {
          C[(size_t)row * N + col] = acc[mi][ni][r] + bb;
        } else {
          const int bidx = row / LQ, pos = row - bidx * LQ;
          const int h = col >> 5, d = col & 31;
          Cbf[((size_t)(bidx * NH + h) * LQ + pos) * HD + d] =
              f2bf(acc[mi][ni][r] + bb);
        }
      }
    }
  }
}

// ---------------------------------------------------------------------------
// One-shot weight prep: transpose + bf16 hi/lo split.
// ---------------------------------------------------------------------------
__global__ __launch_bounds__(256) void convert_W(
    const float* __restrict__ Wv, const float* __restrict__ Woff,
    const float* __restrict__ Watt, const float* __restrict__ Wo,
    const float* __restrict__ boff, const float* __restrict__ batt,
    ushort* __restrict__ WvTh, ushort* __restrict__ WvTl,
    ushort* __restrict__ WcTh, ushort* __restrict__ WcTl,
    ushort* __restrict__ WoTh, ushort* __restrict__ WoTl,
    float* __restrict__ bias288) {
  const int t = blockIdx.x * 256 + threadIdx.x;
  if (t < 256 * 256) {
    const int n = t >> 8, k = t & 255;
    float v = Wv[k * 256 + n];
    ushort h = f2bf(v);
    WvTh[t] = h; WvTl[t] = f2bf(v - bf2f(h));
    float o = Wo[k * 256 + n];
    h = f2bf(o);
    WoTh[t] = h; WoTl[t] = f2bf(o - bf2f(h));
  }
  if (t < 288 * 256) {
    const int n = t >> 8, k = t & 255;
    const float w = (n < 192) ? Woff[k * 192 + n] : Watt[k * 96 + (n - 192)];
    const ushort h = f2bf(w);
    WcTh[t] = h; WcTl[t] = f2bf(w - bf2f(h));
  }
  if (t < 288) bias288[t] = (t < 192) ? boff[t] : batt[t - 192];
}

// ---------------------------------------------------------------------------
// Finalize raw projection [M][288] in place: coords + softmax.
// ---------------------------------------------------------------------------
__global__ __launch_bounds__(256) void finalize(
    float* __restrict__ raw, const float* __restrict__ ref, int M) {
  const int tid = threadIdx.x;
  const int g0 = blockIdx.x * 16;
  const float S_[3] = {100.f, 50.f, 25.f};

  for (int idx = tid; idx < 16 * 192; idx += 256) {
    const int r = idx / 192, col = idx - r * 192;
    const int g = g0 + r;
    if (g >= M) break;
    const int l = (col % 24) >> 3;
    const int xy = col & 1;
    raw[(size_t)g * 288 + col] =
        ref[(size_t)g * 6 + l * 2 + xy] * S_[l] + raw[(size_t)g * 288 + col] - 0.5f;
  }
  if (tid < 128) {
    const int r = tid >> 3, h = tid & 7;
    const int g = g0 + r;
    if (g < M) {
      float* a = raw + (size_t)g * 288 + 192 + h * 12;
      float m = a[0];
#pragma unroll
      for (int j = 1; j < 12; ++j) m = fmaxf(m, a[j]);
      float e[12], s = 0.f;
#pragma unroll
      for (int j = 0; j < 12; ++j) { e[j] = expf(a[j] - m); s += e[j]; }
      const float inv = 1.f / s;
#pragma unroll
      for (int j = 0; j < 12; ++j) a[j] = e[j] * inv;
    }
  }
}

// ---------------------------------------------------------------------------
// Bilinear sampling, bf16 value.  vbf layout: [(b*8+h)][pos][32] bf16.
// 8 lanes per (g,h) group; lane owns 4 channels.  Output mid: bf16 [g][256].
// ---------------------------------------------------------------------------
__global__ __launch_bounds__(256) void deform_sample_bf16(
    const ushort* __restrict__ vbf, const float* __restrict__ raw,
    ushort* __restrict__ mid, int M) {
  const int tid = threadIdx.x;
  const int gidx = blockIdx.x * 32 + (tid >> 3);
  if (gidx >= M * NH) return;
  const int d4 = (tid & 7) << 2;
  const int g = gidx >> 3;
  const int h = gidx & 7;
  const int b = g / LQ;

  const float4* xy4 = (const float4*)(raw + (size_t)g * 288 + h * 24);
  const float4* aw4 = (const float4*)(raw + (size_t)g * 288 + 192 + h * 12);
  float xy[24], aw[12];
#pragma unroll
  for (int i = 0; i < 6; ++i) {
    float4 t = xy4[i];
    xy[4 * i + 0] = t.x; xy[4 * i + 1] = t.y;
    xy[4 * i + 2] = t.z; xy[4 * i + 3] = t.w;
  }
#pragma unroll
  for (int i = 0; i < 3; ++i) {
    float4 t = aw4[i];
    aw[4 * i + 0] = t.x; aw[4 * i + 1] = t.y;
    aw[4 * i + 2] = t.z; aw[4 * i + 3] = t.w;
  }

  const ushort* vb = vbf + ((size_t)(b * NH + h) * LQ) * HD + d4;

  const int Wl_[3] = {100, 50, 25};
  const int loff_[3] = {0, 10000, 12500};

  float4 acc = make_float4(0.f, 0.f, 0.f, 0.f);
#pragma unroll
  for (int l = 0; l < NL; ++l) {
    const int Wl = Wl_[l];
    const ushort* vl = vb + (size_t)loff_[l] * HD;
#pragma unroll
    for (int p = 0; p < NP; ++p) {
      const float x = xy[l * 8 + p * 2 + 0];
      const float y = xy[l * 8 + p * 2 + 1];
      const float w = aw[l * 4 + p];
      const float fx = floorf(x), fy = floorf(y);
      const int x0 = (int)fx, y0 = (int)fy;
      const float wx1 = x - fx, wy1 = y - fy;
      const float wx0 = 1.f - wx1, wy0 = 1.f - wy1;

      const int x0c = min(max(x0, 0), Wl - 1);
      const int x1c = min(max(x0 + 1, 0), Wl - 1);
      const int y0c = min(max(y0, 0), Wl - 1);
      const int y1c = min(max(y0 + 1, 0), Wl - 1);
      const float vx0 = (x0 >= 0 && x0 < Wl) ? wx0 : 0.f;
      const float vx1 = (x0 + 1 >= 0 && x0 + 1 < Wl) ? wx1 : 0.f;
      const float vy0 = (y0 >= 0 && y0 < Wl) ? wy0 : 0.f;
      const float vy1 = (y0 + 1 >= 0 && y0 + 1 < Wl) ? wy1 : 0.f;

      const ushort4 c00 = *(const ushort4*)&vl[(size_t)(y0c * Wl + x0c) * HD];
      const ushort4 c01 = *(const ushort4*)&vl[(size_t)(y0c * Wl + x1c) * HD];
      const ushort4 c10 = *(const ushort4*)&vl[(size_t)(y1c * Wl + x0c) * HD];
      const ushort4 c11 = *(const ushort4*)&vl[(size_t)(y1c * Wl + x1c) * HD];

      const float w00 = w * vy0 * vx0, w01 = w * vy0 * vx1;
      const float w10 = w * vy1 * vx0, w11 = w * vy1 * vx1;
      acc.x += w00 * bf2f(c00.x) + w01 * bf2f(c01.x) + w10 * bf2f(c10.x) + w11 * bf2f(c11.x);
      acc.y += w00 * bf2f(c00.y) + w01 * bf2f(c01.y) + w10 * bf2f(c10.y) + w11 * bf2f(c11.y);
      acc.z += w00 * bf2f(c00.z) + w01 * bf2f(c01.z) + w10 * bf2f(c10.z) + w11 * bf2f(c11.z);
      acc.w += w00 * bf2f(c00.w) + w01 * bf2f(c01.w) + w10 * bf2f(c10.w) + w11 * bf2f(c11.w);
    }
  }
  ushort4 o;
  o.x = f2bf(acc.x); o.y = f2bf(acc.y); o.z = f2bf(acc.z); o.w = f2bf(acc.w);
  *(ushort4*)&mid[(size_t)g * E + h * HD + d4] = o;
}

// ---------------------------------------------------------------------------
extern "C" void kernel_launch(void* const* d_in, const int* in_sizes, int n_in,
                              void* d_out, int out_size, void* d_ws, size_t ws_size,
                              hipStream_t stream) {
  const float* query = (const float*)d_in[0];
  const float* refpt = (const float*)d_in[1];
  const float* value = (const float*)d_in[2];
  const float* Wv   = (const float*)d_in[4];
  const float* bv   = (const float*)d_in[5];
  const float* Woff = (const float*)d_in[6];
  const float* boff = (const float*)d_in[7];
  const float* Watt = (const float*)d_in[8];
  const float* batt = (const float*)d_in[9];
  const float* Wo   = (const float*)d_in[10];
  const float* bo   = (const float*)d_in[11];

  const int M = in_sizes[0] / E;  // B * Lq = 52500

  // workspace layout (~115 MB, same high-water as round 4)
  float* wsf   = (float*)d_ws;
  float* raw   = wsf;                         // M*288 floats
  float* b288  = raw + (size_t)M * 288;       // 288
  ushort* mid  = (ushort*)(b288 + 288);       // M*256 ushorts
  ushort* vbf  = mid + (size_t)M * 256;       // M*256 ushorts
  ushort* wvh  = vbf + (size_t)M * 256;       // 65536 each
  ushort* wvl  = wvh + 65536;
  ushort* woh  = wvl + 65536;
  ushort* wol  = woh + 65536;
  ushort* wch  = wol + 65536;                 // 73728 each
  ushort* wcl  = wch + 73728;

  // A-conversion scratch lives in d_out (M*256 fp32 = M*512 ushorts, exact fit).
  // d_out is dead until the final GEMM writes it.
  ushort* ahi = (ushort*)d_out;
  ushort* alo = ahi + (size_t)M * 256;

  const int gridM = (M + 127) / 128;
  const int convGrid = (M * 64 + 255) / 256;

  // 0. weight prep
  convert_W<<<288, 256, 0, stream>>>(Wv, Woff, Watt, Wo, boff, batt,
                                     wvh, wvl, wch, wcl, woh, wol, b288);
  // 1a. value -> bf16 hi/lo (in d_out)
  convertA<<<convGrid, 256, 0, stream>>>(value, ahi, alo, M * 64);
  // 1b. value projection -> vbf (bf16, head-major); K=768 virtual
  gemm_gl<3, 1><<<dim3(gridM, 2), 256, 0, stream>>>(
      ahi, ahi, alo, wvh, wvl, wvh, bv, nullptr, vbf, M, 256);
  // 2a. query -> bf16 hi/lo (reuse d_out scratch)
  convertA<<<convGrid, 256, 0, stream>>>(query, ahi, alo, M * 64);
  // 2b. offsets+attention raw projection -> raw (fp32); K=768 virtual
  gemm_gl<3, 0><<<dim3(gridM, 3), 256, 0, stream>>>(
      ahi, ahi, alo, wch, wcl, wch, b288, raw, nullptr, M, 288);
  // 3. coords + softmax, in place on raw
  finalize<<<(M + 15) / 16, 256, 0, stream>>>(raw, refpt, M);
  // 4. deformable bilinear sampling -> mid (bf16)
  deform_sample_bf16<<<(M * NH + 31) / 32, 256, 0, stream>>>(vbf, raw, mid, M);
  // 5. output projection: mid (bf16) @ Wo -> d_out (fp32); K=512 virtual
  gemm_gl<2, 0><<<dim3(gridM, 2), 256, 0, stream>>>(
      mid, mid, mid, woh, wol, woh, bo, (float*)d_out, nullptr, M, 256);
}

// Round 6
// 329.752 us; speedup vs baseline: 3.0883x; 1.0147x over previous
//
#include <hip/hip_runtime.h>
#include <hip/hip_bf16.h>

// Problem constants (fixed by the reference)
#define E    256
#define NH   8
#define NL   3
#define NP   4
#define HD   32
#define LQ   13125   // = Lv = 10000 + 2500 + 625

typedef short bf16x8 __attribute__((ext_vector_type(8)));
typedef float f32x4  __attribute__((ext_vector_type(4)));

// round-to-nearest-even fp32 -> bf16 (as ushort bits)
__device__ __forceinline__ ushort f2bf(float x) {
  uint u = __float_as_uint(x);
  uint r = (u + 0x7fffu + ((u >> 16) & 1u)) >> 16;
  return (ushort)r;
}
__device__ __forceinline__ float bf2f(ushort u) {
  return __uint_as_float((uint)u << 16);
}

__device__ __forceinline__ void gl_lds16(const ushort* g, ushort* l) {
  __builtin_amdgcn_global_load_lds(
      (const __attribute__((address_space(1))) void*)g,
      (__attribute__((address_space(3))) void*)l, 16, 0, 0);
}

// ---------------------------------------------------------------------------
// fp32 [M][256] -> bf16 hi/lo [M][256] each (hi = rne(a), lo = rne(a - hi)).
// ---------------------------------------------------------------------------
__global__ __launch_bounds__(256) void convertA(
    const float* __restrict__ A, ushort* __restrict__ hi,
    ushort* __restrict__ lo, int n4) {
  const int i = blockIdx.x * 256 + threadIdx.x;
  if (i >= n4) return;
  const float4 a = ((const float4*)A)[i];
  ushort4 h, l;
  h.x = f2bf(a.x); l.x = f2bf(a.x - bf2f(h.x));
  h.y = f2bf(a.y); l.y = f2bf(a.y - bf2f(h.y));
  h.z = f2bf(a.z); l.z = f2bf(a.z - bf2f(h.z));
  h.w = f2bf(a.w); l.w = f2bf(a.w - bf2f(h.w));
  ((ushort4*)hi)[i] = h;
  ((ushort4*)lo)[i] = l;
}

// ---------------------------------------------------------------------------
// Fused-phase split-bf16 MFMA GEMM (m97 staging, all phases per K-step):
//   NPH==3:  C = Ah*Bh + Ah*Bl + Al*Bh   (fp32-emulated fp32 GEMM)
//   NPH==2:  C = Ah*Bh + Ah*Bl           (A is plain bf16)
// A*: [M][256] bf16 row-major.  B*: [N][256] bf16 (transposed weights).
// Tile 128x128, 4 waves (2x2), BK=32; LDS 4 linear tiles [128][32] staged via
// global_load_lds width-16; 48 (or 32) MFMAs per barrier-pair, 8 K-steps.
// OUT_MODE 0: fp32 C[M][N].  OUT_MODE 1: bf16 head-major value layout
//   Cbf[((b*8 + col>>5)*LQ + pos)*32 + (col&31)],  b=row/LQ, pos=row%LQ.
// ---------------------------------------------------------------------------
template <int NPH, int OUT_MODE>
__global__ __launch_bounds__(256) void gemm_fused(
    const ushort* __restrict__ Ah_, const ushort* __restrict__ Al_,
    const ushort* __restrict__ Bh_, const ushort* __restrict__ Bl_,
    const float* __restrict__ bias, float* __restrict__ C,
    ushort* __restrict__ Cbf, int M, int N) {
  __shared__ ushort AhS[4096];
  __shared__ ushort AlS[4096];
  __shared__ ushort BhS[4096];
  __shared__ ushort BlS[4096];
  const int tid = threadIdx.x;
  const int lane = tid & 63;
  const int wid = tid >> 6;
  const int wm = wid >> 1, wn = wid & 1;
  const int r0 = blockIdx.x * 128;
  const int c0 = blockIdx.y * 128;
  const int l15 = lane & 15;
  const int lhi = lane >> 4;
  const int srow = lane >> 2;        // row within 16-row chunk
  const int skoff = (lane & 3) * 8;  // ushort offset within 32-elem row

  f32x4 acc[4][4] = {};

  for (int kk = 0; kk < 256; kk += 32) {
    // each wave fills LDS chunks {wid, wid+4} of each tile (1 KB per chunk)
#pragma unroll
    for (int j = 0; j < 2; ++j) {
      const int c = wid + j * 4;
      const int arow = min(r0 + c * 16 + srow, M - 1);
      const int brow = min(c0 + c * 16 + srow, N - 1);
      const size_t aoff = (size_t)arow * 256 + kk + skoff;
      const size_t boff = (size_t)brow * 256 + kk + skoff;
      gl_lds16(Ah_ + aoff, AhS + c * 512);
      if constexpr (NPH == 3) gl_lds16(Al_ + aoff, AlS + c * 512);
      gl_lds16(Bh_ + boff, BhS + c * 512);
      gl_lds16(Bl_ + boff, BlS + c * 512);
    }
    __syncthreads();  // drains vmcnt (global_load_lds) before LDS reads

    bf16x8 afh[4], afl[4], bfh[4], bfl[4];
#pragma unroll
    for (int mi = 0; mi < 4; ++mi) {
      const int ro = (wm * 64 + mi * 16 + l15) * 32 + lhi * 8;
      afh[mi] = *(const bf16x8*)&AhS[ro];
      if constexpr (NPH == 3) afl[mi] = *(const bf16x8*)&AlS[ro];
    }
#pragma unroll
    for (int ni = 0; ni < 4; ++ni) {
      const int ro = (wn * 64 + ni * 16 + l15) * 32 + lhi * 8;
      bfh[ni] = *(const bf16x8*)&BhS[ro];
      bfl[ni] = *(const bf16x8*)&BlS[ro];
    }
#pragma unroll
    for (int mi = 0; mi < 4; ++mi)
#pragma unroll
      for (int ni = 0; ni < 4; ++ni) {
        acc[mi][ni] = __builtin_amdgcn_mfma_f32_16x16x32_bf16(
            afh[mi], bfl[ni], acc[mi][ni], 0, 0, 0);
        if constexpr (NPH == 3)
          acc[mi][ni] = __builtin_amdgcn_mfma_f32_16x16x32_bf16(
              afl[mi], bfh[ni], acc[mi][ni], 0, 0, 0);
        acc[mi][ni] = __builtin_amdgcn_mfma_f32_16x16x32_bf16(
            afh[mi], bfh[ni], acc[mi][ni], 0, 0, 0);
      }
    __syncthreads();  // protect LDS from next-iteration staging
  }

  // epilogue: C/D layout col=lane&15, row=(lane>>4)*4+reg (m89-verified)
#pragma unroll
  for (int ni = 0; ni < 4; ++ni) {
    const int col = c0 + wn * 64 + ni * 16 + l15;
    if (col >= N) continue;
    const float bb = bias[col];
#pragma unroll
    for (int mi = 0; mi < 4; ++mi) {
      const int rowb = r0 + wm * 64 + mi * 16 + lhi * 4;
#pragma unroll
      for (int r = 0; r < 4; ++r) {
        const int row = rowb + r;
        if (row >= M) continue;
        if (OUT_MODE == 0) {
          C[(size_t)row * N + col] = acc[mi][ni][r] + bb;
        } else {
          const int bidx = row / LQ, pos = row - bidx * LQ;
          const int h = col >> 5, d = col & 31;
          Cbf[((size_t)(bidx * NH + h) * LQ + pos) * HD + d] =
              f2bf(acc[mi][ni][r] + bb);
        }
      }
    }
  }
}

// ---------------------------------------------------------------------------
// One-shot weight prep: transpose + bf16 hi/lo split.
// ---------------------------------------------------------------------------
__global__ __launch_bounds__(256) void convert_W(
    const float* __restrict__ Wv, const float* __restrict__ Woff,
    const float* __restrict__ Watt, const float* __restrict__ Wo,
    const float* __restrict__ boff, const float* __restrict__ batt,
    ushort* __restrict__ WvTh, ushort* __restrict__ WvTl,
    ushort* __restrict__ WcTh, ushort* __restrict__ WcTl,
    ushort* __restrict__ WoTh, ushort* __restrict__ WoTl,
    float* __restrict__ bias288) {
  const int t = blockIdx.x * 256 + threadIdx.x;
  if (t < 256 * 256) {
    const int n = t >> 8, k = t & 255;
    float v = Wv[k * 256 + n];
    ushort h = f2bf(v);
    WvTh[t] = h; WvTl[t] = f2bf(v - bf2f(h));
    float o = Wo[k * 256 + n];
    h = f2bf(o);
    WoTh[t] = h; WoTl[t] = f2bf(o - bf2f(h));
  }
  if (t < 288 * 256) {
    const int n = t >> 8, k = t & 255;
    const float w = (n < 192) ? Woff[k * 192 + n] : Watt[k * 96 + (n - 192)];
    const ushort h = f2bf(w);
    WcTh[t] = h; WcTl[t] = f2bf(w - bf2f(h));
  }
  if (t < 288) bias288[t] = (t < 192) ? boff[t] : batt[t - 192];
}

// ---------------------------------------------------------------------------
// Finalize raw projection [M][288] in place: coords + softmax.
// ---------------------------------------------------------------------------
__global__ __launch_bounds__(256) void finalize(
    float* __restrict__ raw, const float* __restrict__ ref, int M) {
  const int tid = threadIdx.x;
  const int g0 = blockIdx.x * 16;
  const float S_[3] = {100.f, 50.f, 25.f};

  for (int idx = tid; idx < 16 * 192; idx += 256) {
    const int r = idx / 192, col = idx - r * 192;
    const int g = g0 + r;
    if (g >= M) break;
    const int l = (col % 24) >> 3;
    const int xy = col & 1;
    raw[(size_t)g * 288 + col] =
        ref[(size_t)g * 6 + l * 2 + xy] * S_[l] + raw[(size_t)g * 288 + col] - 0.5f;
  }
  if (tid < 128) {
    const int r = tid >> 3, h = tid & 7;
    const int g = g0 + r;
    if (g < M) {
      float* a = raw + (size_t)g * 288 + 192 + h * 12;
      float m = a[0];
#pragma unroll
      for (int j = 1; j < 12; ++j) m = fmaxf(m, a[j]);
      float e[12], s = 0.f;
#pragma unroll
      for (int j = 0; j < 12; ++j) { e[j] = expf(a[j] - m); s += e[j]; }
      const float inv = 1.f / s;
#pragma unroll
      for (int j = 0; j < 12; ++j) a[j] = e[j] * inv;
    }
  }
}

// ---------------------------------------------------------------------------
// Bilinear sampling v2: 4 lanes per (g,h) group, 8 channels/lane.
// Corner loads are uint4 (16B) -> group covers the full 64B slice in one inst.
// Channel accumulation as float2 pairs (packed-FMA friendly); bf16->f32 via
// 2 bit-ops per pair.  Output mid: bf16 [g][256], one uint4 store per lane.
// ---------------------------------------------------------------------------
__device__ __forceinline__ float2 bfpair(uint u) {
  float2 f;
  f.x = __uint_as_float(u << 16);
  f.y = __uint_as_float(u & 0xffff0000u);
  return f;
}

__global__ __launch_bounds__(256) void deform_sample_v2(
    const ushort* __restrict__ vbf, const float* __restrict__ raw,
    ushort* __restrict__ mid, int M) {
  const int tid = threadIdx.x;
  const int gidx = blockIdx.x * 64 + (tid >> 2);
  if (gidx >= M * NH) return;
  const int d8 = (tid & 3) << 3;   // 8 channels per lane
  const int g = gidx >> 3;
  const int h = gidx & 7;
  const int b = g / LQ;

  const float4* xy4 = (const float4*)(raw + (size_t)g * 288 + h * 24);
  const float4* aw4 = (const float4*)(raw + (size_t)g * 288 + 192 + h * 12);
  float xy[24], aw[12];
#pragma unroll
  for (int i = 0; i < 6; ++i) {
    float4 t = xy4[i];
    xy[4 * i + 0] = t.x; xy[4 * i + 1] = t.y;
    xy[4 * i + 2] = t.z; xy[4 * i + 3] = t.w;
  }
#pragma unroll
  for (int i = 0; i < 3; ++i) {
    float4 t = aw4[i];
    aw[4 * i + 0] = t.x; aw[4 * i + 1] = t.y;
    aw[4 * i + 2] = t.z; aw[4 * i + 3] = t.w;
  }

  const ushort* vb = vbf + ((size_t)(b * NH + h) * LQ) * HD + d8;

  const int Wl_[3] = {100, 50, 25};
  const int loff_[3] = {0, 10000, 12500};

  float2 acc0 = {0.f, 0.f}, acc1 = {0.f, 0.f};
  float2 acc2 = {0.f, 0.f}, acc3 = {0.f, 0.f};

#define ACCP(q, wgt) do {                                          \
    float2 f_;                                                     \
    f_ = bfpair((q).x); acc0.x += (wgt) * f_.x; acc0.y += (wgt) * f_.y; \
    f_ = bfpair((q).y); acc1.x += (wgt) * f_.x; acc1.y += (wgt) * f_.y; \
    f_ = bfpair((q).z); acc2.x += (wgt) * f_.x; acc2.y += (wgt) * f_.y; \
    f_ = bfpair((q).w); acc3.x += (wgt) * f_.x; acc3.y += (wgt) * f_.y; \
  } while (0)

#pragma unroll
  for (int l = 0; l < NL; ++l) {
    const int Wl = Wl_[l];
    const ushort* vl = vb + (size_t)loff_[l] * HD;
#pragma unroll
    for (int p = 0; p < NP; ++p) {
      const float x = xy[l * 8 + p * 2 + 0];
      const float y = xy[l * 8 + p * 2 + 1];
      const float w = aw[l * 4 + p];
      const float fx = floorf(x), fy = floorf(y);
      const int x0 = (int)fx, y0 = (int)fy;
      const float wx1 = x - fx, wy1 = y - fy;
      const float wx0 = 1.f - wx1, wy0 = 1.f - wy1;

      const int x0c = min(max(x0, 0), Wl - 1);
      const int x1c = min(max(x0 + 1, 0), Wl - 1);
      const int y0c = min(max(y0, 0), Wl - 1);
      const int y1c = min(max(y0 + 1, 0), Wl - 1);
      const float vx0 = (x0 >= 0 && x0 < Wl) ? wx0 : 0.f;
      const float vx1 = (x0 + 1 >= 0 && x0 + 1 < Wl) ? wx1 : 0.f;
      const float vy0 = (y0 >= 0 && y0 < Wl) ? wy0 : 0.f;
      const float vy1 = (y0 + 1 >= 0 && y0 + 1 < Wl) ? wy1 : 0.f;

      const ushort* r0p = vl + (size_t)(y0c * Wl) * HD;
      const ushort* r1p = vl + (size_t)(y1c * Wl) * HD;
      const uint4 q00 = *(const uint4*)&r0p[x0c * HD];
      const uint4 q01 = *(const uint4*)&r0p[x1c * HD];
      const uint4 q10 = *(const uint4*)&r1p[x0c * HD];
      const uint4 q11 = *(const uint4*)&r1p[x1c * HD];

      const float w00 = w * vy0 * vx0, w01 = w * vy0 * vx1;
      const float w10 = w * vy1 * vx0, w11 = w * vy1 * vx1;
      ACCP(q00, w00);
      ACCP(q01, w01);
      ACCP(q10, w10);
      ACCP(q11, w11);
    }
  }
#undef ACCP

  uint4 o;
  o.x = (uint)f2bf(acc0.x) | ((uint)f2bf(acc0.y) << 16);
  o.y = (uint)f2bf(acc1.x) | ((uint)f2bf(acc1.y) << 16);
  o.z = (uint)f2bf(acc2.x) | ((uint)f2bf(acc2.y) << 16);
  o.w = (uint)f2bf(acc3.x) | ((uint)f2bf(acc3.y) << 16);
  *(uint4*)&mid[(size_t)g * E + h * HD + d8] = o;
}

// ---------------------------------------------------------------------------
extern "C" void kernel_launch(void* const* d_in, const int* in_sizes, int n_in,
                              void* d_out, int out_size, void* d_ws, size_t ws_size,
                              hipStream_t stream) {
  const float* query = (const float*)d_in[0];
  const float* refpt = (const float*)d_in[1];
  const float* value = (const float*)d_in[2];
  const float* Wv   = (const float*)d_in[4];
  const float* bv   = (const float*)d_in[5];
  const float* Woff = (const float*)d_in[6];
  const float* boff = (const float*)d_in[7];
  const float* Watt = (const float*)d_in[8];
  const float* batt = (const float*)d_in[9];
  const float* Wo   = (const float*)d_in[10];
  const float* bo   = (const float*)d_in[11];

  const int M = in_sizes[0] / E;  // B * Lq = 52500

  // workspace layout (~116 MB)
  float* wsf   = (float*)d_ws;
  float* raw   = wsf;                         // M*288 floats
  float* b288  = raw + (size_t)M * 288;       // 288
  ushort* mid  = (ushort*)(b288 + 288);       // M*256 ushorts
  ushort* vbf  = mid + (size_t)M * 256;       // M*256 ushorts
  ushort* wvh  = vbf + (size_t)M * 256;       // 65536 each
  ushort* wvl  = wvh + 65536;
  ushort* woh  = wvl + 65536;
  ushort* wol  = woh + 65536;
  ushort* wch  = wol + 65536;                 // 73728 each
  ushort* wcl  = wch + 73728;

  // A-conversion scratch lives in d_out (M*256 fp32 = M*512 ushorts, exact fit).
  // d_out is dead until the final GEMM writes it.
  ushort* ahi = (ushort*)d_out;
  ushort* alo = ahi + (size_t)M * 256;

  const int gridM = (M + 127) / 128;
  const int convGrid = (M * 64 + 255) / 256;

  // 0. weight prep
  convert_W<<<288, 256, 0, stream>>>(Wv, Woff, Watt, Wo, boff, batt,
                                     wvh, wvl, wch, wcl, woh, wol, b288);
  // 1a. value -> bf16 hi/lo (in d_out)
  convertA<<<convGrid, 256, 0, stream>>>(value, ahi, alo, M * 64);
  // 1b. value projection -> vbf (bf16, head-major); 3 fused phases
  gemm_fused<3, 1><<<dim3(gridM, 2), 256, 0, stream>>>(
      ahi, alo, wvh, wvl, bv, nullptr, vbf, M, 256);
  // 2a. query -> bf16 hi/lo (reuse d_out scratch)
  convertA<<<convGrid, 256, 0, stream>>>(query, ahi, alo, M * 64);
  // 2b. offsets+attention raw projection -> raw (fp32); 3 fused phases
  gemm_fused<3, 0><<<dim3(gridM, 3), 256, 0, stream>>>(
      ahi, alo, wch, wcl, b288, raw, nullptr, M, 288);
  // 3. coords + softmax, in place on raw
  finalize<<<(M + 15) / 16, 256, 0, stream>>>(raw, refpt, M);
  // 4. deformable bilinear sampling -> mid (bf16)
  deform_sample_v2<<<(M * NH + 63) / 64, 256, 0, stream>>>(vbf, raw, mid, M);
  // 5. output projection: mid (bf16) @ Wo -> d_out (fp32); 2 fused phases
  gemm_fused<2, 0><<<dim3(gridM, 2), 256, 0, stream>>>(
      mid, nullptr, woh, wol, bo, (float*)d_out, nullptr, M, 256);
}

// Round 7
// 268.123 us; speedup vs baseline: 3.7982x; 1.2299x over previous
//
#include <hip/hip_runtime.h>
#include <hip/hip_bf16.h>

// Problem constants (fixed by the reference)
#define E    256
#define NH   8
#define NL   3
#define NP   4
#define HD   32
#define LQ   13125   // = Lv = 10000 + 2500 + 625

typedef short bf16x8 __attribute__((ext_vector_type(8)));
typedef float f32x4  __attribute__((ext_vector_type(4)));

// round-to-nearest-even fp32 -> bf16 (as ushort bits)
__device__ __forceinline__ ushort f2bf(float x) {
  uint u = __float_as_uint(x);
  uint r = (u + 0x7fffu + ((u >> 16) & 1u)) >> 16;
  return (ushort)r;
}
__device__ __forceinline__ float bf2f(ushort u) {
  return __uint_as_float((uint)u << 16);
}

__device__ __forceinline__ void gl_lds16(const ushort* g, ushort* l) {
  __builtin_amdgcn_global_load_lds(
      (const __attribute__((address_space(1))) void*)g,
      (__attribute__((address_space(3))) void*)l, 16, 0, 0);
}

// ---------------------------------------------------------------------------
// fp32 [M][256] -> bf16 (hi only), vectorized.
// ---------------------------------------------------------------------------
__global__ __launch_bounds__(256) void convertA_hi(
    const float* __restrict__ A, ushort* __restrict__ hi, int n4) {
  const int i = blockIdx.x * 256 + threadIdx.x;
  if (i >= n4) return;
  const float4 a = ((const float4*)A)[i];
  ushort4 h;
  h.x = f2bf(a.x); h.y = f2bf(a.y); h.z = f2bf(a.z); h.w = f2bf(a.w);
  ((ushort4*)hi)[i] = h;
}

// ---------------------------------------------------------------------------
// Single-phase bf16 MFMA GEMM (m97 structure): C = A @ B^T + bias.
// A: [M][256] bf16 row-major.  B: [N][256] bf16 (transposed weights).
// Tile 128x128, 4 waves (2x2), BK=32; LDS 2 linear tiles [128][32] staged via
// global_load_lds width-16; 16 MFMAs per barrier-pair, 8 K-steps.
// OUT_MODE 0: fp32 C[M][N].  OUT_MODE 1: bf16 head-major value layout
//   Cbf[((b*8 + col>>5)*LQ + pos)*32 + (col&31)],  b=row/LQ, pos=row%LQ.
// ---------------------------------------------------------------------------
template <int OUT_MODE>
__global__ __launch_bounds__(256) void gemm_bf16(
    const ushort* __restrict__ A_, const ushort* __restrict__ B_,
    const float* __restrict__ bias, float* __restrict__ C,
    ushort* __restrict__ Cbf, int M, int N) {
  __shared__ ushort As[4096];
  __shared__ ushort Bs[4096];
  const int tid = threadIdx.x;
  const int lane = tid & 63;
  const int wid = tid >> 6;
  const int wm = wid >> 1, wn = wid & 1;
  const int r0 = blockIdx.x * 128;
  const int c0 = blockIdx.y * 128;
  const int l15 = lane & 15;
  const int lhi = lane >> 4;
  const int srow = lane >> 2;        // row within 16-row chunk
  const int skoff = (lane & 3) * 8;  // ushort offset within 32-elem row

  f32x4 acc[4][4] = {};

  for (int kk = 0; kk < 256; kk += 32) {
    // each wave fills LDS chunks {wid, wid+4} of A and B (1 KB per chunk)
#pragma unroll
    for (int j = 0; j < 2; ++j) {
      const int c = wid + j * 4;
      const int arow = min(r0 + c * 16 + srow, M - 1);
      const int brow = min(c0 + c * 16 + srow, N - 1);
      gl_lds16(A_ + (size_t)arow * 256 + kk + skoff, As + c * 512);
      gl_lds16(B_ + (size_t)brow * 256 + kk + skoff, Bs + c * 512);
    }
    __syncthreads();  // drains vmcnt (global_load_lds) before LDS reads

    bf16x8 af[4], bf[4];
#pragma unroll
    for (int mi = 0; mi < 4; ++mi)
      af[mi] = *(const bf16x8*)&As[(wm * 64 + mi * 16 + l15) * 32 + lhi * 8];
#pragma unroll
    for (int ni = 0; ni < 4; ++ni)
      bf[ni] = *(const bf16x8*)&Bs[(wn * 64 + ni * 16 + l15) * 32 + lhi * 8];
#pragma unroll
    for (int mi = 0; mi < 4; ++mi)
#pragma unroll
      for (int ni = 0; ni < 4; ++ni)
        acc[mi][ni] = __builtin_amdgcn_mfma_f32_16x16x32_bf16(
            af[mi], bf[ni], acc[mi][ni], 0, 0, 0);
    __syncthreads();  // protect LDS from next-iteration staging
  }

  // epilogue: C/D layout col=lane&15, row=(lane>>4)*4+reg (m89-verified)
#pragma unroll
  for (int ni = 0; ni < 4; ++ni) {
    const int col = c0 + wn * 64 + ni * 16 + l15;
    if (col >= N) continue;
    const float bb = bias[col];
#pragma unroll
    for (int mi = 0; mi < 4; ++mi) {
      const int rowb = r0 + wm * 64 + mi * 16 + lhi * 4;
#pragma unroll
      for (int r = 0; r < 4; ++r) {
        const int row = rowb + r;
        if (row >= M) continue;
        if (OUT_MODE == 0) {
          C[(size_t)row * N + col] = acc[mi][ni][r] + bb;
        } else {
          const int bidx = row / LQ, pos = row - bidx * LQ;
          const int h = col >> 5, d = col & 31;
          Cbf[((size_t)(bidx * NH + h) * LQ + pos) * HD + d] =
              f2bf(acc[mi][ni][r] + bb);
        }
      }
    }
  }
}

// ---------------------------------------------------------------------------
// One-shot weight prep: transpose + bf16 (hi only).
// ---------------------------------------------------------------------------
__global__ __launch_bounds__(256) void convert_W(
    const float* __restrict__ Wv, const float* __restrict__ Woff,
    const float* __restrict__ Watt, const float* __restrict__ Wo,
    const float* __restrict__ boff, const float* __restrict__ batt,
    ushort* __restrict__ WvT, ushort* __restrict__ WcT,
    ushort* __restrict__ WoT, float* __restrict__ bias288) {
  const int t = blockIdx.x * 256 + threadIdx.x;
  if (t < 256 * 256) {
    const int n = t >> 8, k = t & 255;
    WvT[t] = f2bf(Wv[k * 256 + n]);
    WoT[t] = f2bf(Wo[k * 256 + n]);
  }
  if (t < 288 * 256) {
    const int n = t >> 8, k = t & 255;
    const float w = (n < 192) ? Woff[k * 192 + n] : Watt[k * 96 + (n - 192)];
    WcT[t] = f2bf(w);
  }
  if (t < 288) bias288[t] = (t < 192) ? boff[t] : batt[t - 192];
}

// ---------------------------------------------------------------------------
// Finalize raw projection [M][288] in place: coords + softmax.
// ---------------------------------------------------------------------------
__global__ __launch_bounds__(256) void finalize(
    float* __restrict__ raw, const float* __restrict__ ref, int M) {
  const int tid = threadIdx.x;
  const int g0 = blockIdx.x * 16;
  const float S_[3] = {100.f, 50.f, 25.f};

  for (int idx = tid; idx < 16 * 192; idx += 256) {
    const int r = idx / 192, col = idx - r * 192;
    const int g = g0 + r;
    if (g >= M) break;
    const int l = (col % 24) >> 3;
    const int xy = col & 1;
    raw[(size_t)g * 288 + col] =
        ref[(size_t)g * 6 + l * 2 + xy] * S_[l] + raw[(size_t)g * 288 + col] - 0.5f;
  }
  if (tid < 128) {
    const int r = tid >> 3, h = tid & 7;
    const int g = g0 + r;
    if (g < M) {
      float* a = raw + (size_t)g * 288 + 192 + h * 12;
      float m = a[0];
#pragma unroll
      for (int j = 1; j < 12; ++j) m = fmaxf(m, a[j]);
      float e[12], s = 0.f;
#pragma unroll
      for (int j = 0; j < 12; ++j) { e[j] = expf(a[j] - m); s += e[j]; }
      const float inv = 1.f / s;
#pragma unroll
      for (int j = 0; j < 12; ++j) a[j] = e[j] * inv;
    }
  }
}

// ---------------------------------------------------------------------------
// Bilinear sampling, bf16 value (round-5 proven structure).
// vbf layout: [(b*8+h)][pos][32] bf16.  8 lanes per (g,h) group; lane owns
// 4 channels (ushort4 = 8B per corner load).  Output mid: bf16 [g][256].
// ---------------------------------------------------------------------------
__global__ __launch_bounds__(256) void deform_sample_bf16(
    const ushort* __restrict__ vbf, const float* __restrict__ raw,
    ushort* __restrict__ mid, int M) {
  const int tid = threadIdx.x;
  const int gidx = blockIdx.x * 32 + (tid >> 3);
  if (gidx >= M * NH) return;
  const int d4 = (tid & 7) << 2;
  const int g = gidx >> 3;
  const int h = gidx & 7;
  const int b = g / LQ;

  const float4* xy4 = (const float4*)(raw + (size_t)g * 288 + h * 24);
  const float4* aw4 = (const float4*)(raw + (size_t)g * 288 + 192 + h * 12);
  float xy[24], aw[12];
#pragma unroll
  for (int i = 0; i < 6; ++i) {
    float4 t = xy4[i];
    xy[4 * i + 0] = t.x; xy[4 * i + 1] = t.y;
    xy[4 * i + 2] = t.z; xy[4 * i + 3] = t.w;
  }
#pragma unroll
  for (int i = 0; i < 3; ++i) {
    float4 t = aw4[i];
    aw[4 * i + 0] = t.x; aw[4 * i + 1] = t.y;
    aw[4 * i + 2] = t.z; aw[4 * i + 3] = t.w;
  }

  const ushort* vb = vbf + ((size_t)(b * NH + h) * LQ) * HD + d4;

  const int Wl_[3] = {100, 50, 25};
  const int loff_[3] = {0, 10000, 12500};

  float4 acc = make_float4(0.f, 0.f, 0.f, 0.f);
#pragma unroll
  for (int l = 0; l < NL; ++l) {
    const int Wl = Wl_[l];
    const ushort* vl = vb + (size_t)loff_[l] * HD;
#pragma unroll
    for (int p = 0; p < NP; ++p) {
      const float x = xy[l * 8 + p * 2 + 0];
      const float y = xy[l * 8 + p * 2 + 1];
      const float w = aw[l * 4 + p];
      const float fx = floorf(x), fy = floorf(y);
      const int x0 = (int)fx, y0 = (int)fy;
      const float wx1 = x - fx, wy1 = y - fy;
      const float wx0 = 1.f - wx1, wy0 = 1.f - wy1;

      const int x0c = min(max(x0, 0), Wl - 1);
      const int x1c = min(max(x0 + 1, 0), Wl - 1);
      const int y0c = min(max(y0, 0), Wl - 1);
      const int y1c = min(max(y0 + 1, 0), Wl - 1);
      const float vx0 = (x0 >= 0 && x0 < Wl) ? wx0 : 0.f;
      const float vx1 = (x0 + 1 >= 0 && x0 + 1 < Wl) ? wx1 : 0.f;
      const float vy0 = (y0 >= 0 && y0 < Wl) ? wy0 : 0.f;
      const float vy1 = (y0 + 1 >= 0 && y0 + 1 < Wl) ? wy1 : 0.f;

      const ushort4 c00 = *(const ushort4*)&vl[(size_t)(y0c * Wl + x0c) * HD];
      const ushort4 c01 = *(const ushort4*)&vl[(size_t)(y0c * Wl + x1c) * HD];
      const ushort4 c10 = *(const ushort4*)&vl[(size_t)(y1c * Wl + x0c) * HD];
      const ushort4 c11 = *(const ushort4*)&vl[(size_t)(y1c * Wl + x1c) * HD];

      const float w00 = w * vy0 * vx0, w01 = w * vy0 * vx1;
      const float w10 = w * vy1 * vx0, w11 = w * vy1 * vx1;
      acc.x += w00 * bf2f(c00.x) + w01 * bf2f(c01.x) + w10 * bf2f(c10.x) + w11 * bf2f(c11.x);
      acc.y += w00 * bf2f(c00.y) + w01 * bf2f(c01.y) + w10 * bf2f(c10.y) + w11 * bf2f(c11.y);
      acc.z += w00 * bf2f(c00.z) + w01 * bf2f(c01.z) + w10 * bf2f(c10.z) + w11 * bf2f(c11.z);
      acc.w += w00 * bf2f(c00.w) + w01 * bf2f(c01.w) + w10 * bf2f(c10.w) + w11 * bf2f(c11.w);
    }
  }
  ushort4 o;
  o.x = f2bf(acc.x); o.y = f2bf(acc.y); o.z = f2bf(acc.z); o.w = f2bf(acc.w);
  *(ushort4*)&mid[(size_t)g * E + h * HD + d4] = o;
}

// ---------------------------------------------------------------------------
extern "C" void kernel_launch(void* const* d_in, const int* in_sizes, int n_in,
                              void* d_out, int out_size, void* d_ws, size_t ws_size,
                              hipStream_t stream) {
  const float* query = (const float*)d_in[0];
  const float* refpt = (const float*)d_in[1];
  const float* value = (const float*)d_in[2];
  const float* Wv   = (const float*)d_in[4];
  const float* bv   = (const float*)d_in[5];
  const float* Woff = (const float*)d_in[6];
  const float* boff = (const float*)d_in[7];
  const float* Watt = (const float*)d_in[8];
  const float* batt = (const float*)d_in[9];
  const float* Wo   = (const float*)d_in[10];
  const float* bo   = (const float*)d_in[11];

  const int M = in_sizes[0] / E;  // B * Lq = 52500

  // workspace layout (~90 MB)
  float* wsf   = (float*)d_ws;
  float* raw   = wsf;                         // M*288 floats
  float* b288  = raw + (size_t)M * 288;       // 288
  ushort* mid  = (ushort*)(b288 + 288);       // M*256 ushorts
  ushort* vbf  = mid + (size_t)M * 256;       // M*256 ushorts
  ushort* wvT  = vbf + (size_t)M * 256;       // 65536
  ushort* woT  = wvT + 65536;                 // 65536
  ushort* wcT  = woT + 65536;                 // 73728

  // bf16 A-operands live in d_out (2 x M*256 ushorts = exact fit).
  // d_out is dead until the final GEMM writes it (by which time both are dead).
  ushort* vhi = (ushort*)d_out;
  ushort* qhi = vhi + (size_t)M * 256;

  const int gridM = (M + 127) / 128;
  const int convGrid = (M * 64 + 255) / 256;

  // 0. weight prep (bf16 hi only)
  convert_W<<<288, 256, 0, stream>>>(Wv, Woff, Watt, Wo, boff, batt,
                                     wvT, wcT, woT, b288);
  // 1a. value -> bf16
  convertA_hi<<<convGrid, 256, 0, stream>>>(value, vhi, M * 64);
  // 1b. value projection -> vbf (bf16, head-major)
  gemm_bf16<1><<<dim3(gridM, 2), 256, 0, stream>>>(
      vhi, wvT, bv, nullptr, vbf, M, 256);
  // 2a. query -> bf16
  convertA_hi<<<convGrid, 256, 0, stream>>>(query, qhi, M * 64);
  // 2b. offsets+attention raw projection -> raw (fp32)
  gemm_bf16<0><<<dim3(gridM, 3), 256, 0, stream>>>(
      qhi, wcT, b288, raw, nullptr, M, 288);
  // 3. coords + softmax, in place on raw
  finalize<<<(M + 15) / 16, 256, 0, stream>>>(raw, refpt, M);
  // 4. deformable bilinear sampling -> mid (bf16)
  deform_sample_bf16<<<(M * NH + 31) / 32, 256, 0, stream>>>(vbf, raw, mid, M);
  // 5. output projection: mid (bf16) @ Wo -> d_out (fp32)
  gemm_bf16<0><<<dim3(gridM, 2), 256, 0, stream>>>(
      mid, woT, bo, (float*)d_out, nullptr, M, 256);
}